// Round 7
// baseline (288.237 us; speedup 1.0000x reference)
//
#include <hip/hip_runtime.h>
#include <math.h>
#include <stdint.h>

// MFMA fragment types (guide §3, compile-verified on gfx950)
typedef __attribute__((ext_vector_type(8))) short bf16x8;   // 8 bf16 in 4 VGPRs
typedef __attribute__((ext_vector_type(4))) float f32x4;    // 4 fp32 acc

__device__ __forceinline__ unsigned short f2bf(float f) {
    union { float f; unsigned u; } v; v.f = f;
    return (unsigned short)((v.u + 0x7fffu + ((v.u >> 16) & 1u)) >> 16); // RNE
}

// async global->LDS, 16B per lane; LDS dest = wave-uniform base + lane*16 (m97)
__device__ __forceinline__ void gld_lds16(const void* g, void* l) {
    __builtin_amdgcn_global_load_lds(
        (const __attribute__((address_space(1))) unsigned*)(uintptr_t)g,
        (__attribute__((address_space(3))) unsigned*)(uintptr_t)l, 16, 0, 0);
}

// ---------------- fp32 -> bf16 elementwise (x4 vectorized) ----------------
__global__ void k_convert(const float* __restrict__ in, unsigned short* __restrict__ out, int n4) {
    int i = blockIdx.x * blockDim.x + threadIdx.x;
    if (i >= n4) return;
    float4 f = ((const float4*)in)[i];
    ushort4 o;
    o.x = f2bf(f.x); o.y = f2bf(f.y); o.z = f2bf(f.z); o.w = f2bf(f.w);
    ((ushort4*)out)[i] = o;
}

// ---------------- fp32 [R][C] -> bf16 [C][R] (tiled transpose) ----------------
__global__ void k_transpose(const float* __restrict__ in, unsigned short* __restrict__ out, int R, int C) {
    __shared__ float tile[32][33];
    int c0 = blockIdx.x * 32, r0 = blockIdx.y * 32;
    int tx = threadIdx.x, ty = threadIdx.y; // block (32,8)
#pragma unroll
    for (int i = 0; i < 4; ++i)
        tile[ty + i * 8][tx] = in[(size_t)(r0 + ty + i * 8) * C + c0 + tx];
    __syncthreads();
#pragma unroll
    for (int i = 0; i < 4; ++i)
        out[(size_t)(c0 + ty + i * 8) * R + r0 + tx] = f2bf(tile[tx][ty + i * 8]);
}

// ---------------- 128x128 bf16 MFMA GEMM core (m97-style staging) ----------
#define LDT 32

__device__ __forceinline__ void gemm_core(
    const unsigned short* __restrict__ A, const unsigned short* __restrict__ Bt,
    int K, unsigned short* As, unsigned short* Bs, f32x4 (&acc)[4][4])
{
    const int tid  = threadIdx.x;
    const int lane = tid & 63;
    const int w    = tid >> 6;
    const int wm   = (w >> 1) * 64, wn = (w & 1) * 64;
    const int l15  = lane & 15, quad = lane >> 4;
    const int m0 = blockIdx.x * 128, n0 = blockIdx.y * 128;

    const f32x4 zero = {0.f, 0.f, 0.f, 0.f};
#pragma unroll
    for (int i = 0; i < 4; ++i)
#pragma unroll
        for (int j = 0; j < 4; ++j) acc[i][j] = zero;

    const int r0 = tid >> 2, p8 = (tid & 3) * 8;
    const unsigned short* Ag0 = A  + (size_t)(m0 + r0) * K + p8;
    const unsigned short* Ag1 = A  + (size_t)(m0 + r0 + 64) * K + p8;
    const unsigned short* Bg0 = Bt + (size_t)(n0 + r0) * K + p8;
    const unsigned short* Bg1 = Bt + (size_t)(n0 + r0 + 64) * K + p8;
    unsigned short* lA0 = As + r0 * LDT + p8;          // byte offset tid*16
    unsigned short* lA1 = lA0 + 64 * LDT;
    unsigned short* lB0 = Bs + r0 * LDT + p8;
    unsigned short* lB1 = lB0 + 64 * LDT;

    const int nk = K >> 5;
    for (int kt = 0; kt < nk; ++kt) {
        __syncthreads();                    // LDS free (prev compute done)
        gld_lds16(Ag0, lA0);
        gld_lds16(Ag1, lA1);
        gld_lds16(Bg0, lB0);
        gld_lds16(Bg1, lB1);
        Ag0 += 32; Ag1 += 32; Bg0 += 32; Bg1 += 32;
        __syncthreads();                    // drains vmcnt -> data landed
        bf16x8 af[4], bfr[4];
#pragma unroll
        for (int mi = 0; mi < 4; ++mi)
            af[mi] = *(const bf16x8*)&As[(wm + mi * 16 + l15) * LDT + quad * 8];
#pragma unroll
        for (int nj = 0; nj < 4; ++nj)
            bfr[nj] = *(const bf16x8*)&Bs[(wn + nj * 16 + l15) * LDT + quad * 8];
#pragma unroll
        for (int mi = 0; mi < 4; ++mi)
#pragma unroll
            for (int nj = 0; nj < 4; ++nj)
                acc[mi][nj] = __builtin_amdgcn_mfma_f32_16x16x32_bf16(af[mi], bfr[nj], acc[mi][nj], 0, 0, 0);
    }
}

// QKV GEMM epilogue scatters into FRAGMENT-ORDER buffers so every attention
// global load is one coalesced 1024B block (base + lane*16B):
//  QL[bh][qi][m][h][lane][8]  : lane(l15,quad) holds Q[qi*32+16m+l15][32h+8quad+j]
//  KL[bh][t ][i][h][lane][8]  : lane holds K[64t+16i+l15][32h+8quad+j]
//  VL[bh][t ][dj][h][lane][8] : lane holds V[64t+32h+8quad+j][16dj+l15]
// Q pre-scaled by (1/8)*log2(e): softmax runs in exp2 domain.
__global__ __launch_bounds__(256) void k_gemm_qkv(
    const unsigned short* __restrict__ A, const unsigned short* __restrict__ Bt,
    const float* __restrict__ bias,
    unsigned short* __restrict__ QL, unsigned short* __restrict__ KL,
    unsigned short* __restrict__ VL)
{
    __shared__ __align__(16) unsigned short As[128 * LDT];
    __shared__ __align__(16) unsigned short Bs[128 * LDT];
    f32x4 acc[4][4];
    gemm_core(A, Bt, 768, As, Bs, acc);

    const int tid = threadIdx.x, lane = tid & 63, w = tid >> 6;
    const int wm = (w >> 1) * 64, wn = (w & 1) * 64;
    const int l15 = lane & 15, quad = lane >> 4;
    const int m0 = blockIdx.x * 128, n0 = blockIdx.y * 128;
    const float cscale = 0.18033688011f;  // (1/8) * log2(e)
#pragma unroll
    for (int nj = 0; nj < 4; ++nj) {
        int cg = n0 + wn + nj * 16 + l15;        // column in [0,2304)
        float bv = bias[cg];
        int which = cg / 768;                    // 0=q 1=k 2=v
        int rem = cg - which * 768;
        int hd = rem >> 6, d = rem & 63;
        float sc = (which == 0) ? cscale : 1.0f;
#pragma unroll
        for (int mi = 0; mi < 4; ++mi) {
#pragma unroll
            for (int r = 0; r < 4; ++r) {
                int rg = m0 + wm + mi * 16 + quad * 4 + r;   // row in [0,8192)
                int b = rg >> 12, tk = rg & 4095;
                int bh = b * 12 + hd;
                unsigned short ob = f2bf((acc[mi][nj][r] + bv) * sc);
                if (which == 0) {
                    size_t idx = ((((size_t)bh * 128 + (tk >> 5)) * 2 + ((tk >> 4) & 1)) * 2 + (d >> 5)) * 512
                               + ((d >> 3) & 3) * 128 + (tk & 15) * 8 + (d & 7);
                    QL[idx] = ob;
                } else if (which == 1) {
                    size_t idx = ((((size_t)bh * 64 + (tk >> 6)) * 4 + ((tk >> 4) & 3)) * 2 + (d >> 5)) * 512
                               + ((d >> 3) & 3) * 128 + (tk & 15) * 8 + (d & 7);
                    KL[idx] = ob;
                } else {
                    int wi = tk & 63;
                    size_t idx = ((((size_t)bh * 64 + (tk >> 6)) * 4 + (d >> 4)) * 2 + (wi >> 5)) * 512
                               + ((wi >> 3) & 3) * 128 + (d & 15) * 8 + (wi & 7);
                    VL[idx] = ob;
                }
            }
        }
    }
}

// Proj GEMM: A = y bf16 [8192][768], Bt = WprojT [768][768], out fp32 + bias
__global__ __launch_bounds__(256) void k_gemm_proj(
    const unsigned short* __restrict__ A, const unsigned short* __restrict__ Bt,
    const float* __restrict__ bias, float* __restrict__ out)
{
    __shared__ __align__(16) unsigned short As[128 * LDT];
    __shared__ __align__(16) unsigned short Bs[128 * LDT];
    f32x4 acc[4][4];
    gemm_core(A, Bt, 768, As, Bs, acc);

    const int tid = threadIdx.x, lane = tid & 63, w = tid >> 6;
    const int wm = (w >> 1) * 64, wn = (w & 1) * 64;
    const int l15 = lane & 15, quad = lane >> 4;
    const int m0 = blockIdx.x * 128, n0 = blockIdx.y * 128;
#pragma unroll
    for (int nj = 0; nj < 4; ++nj) {
        int cg = n0 + wn + nj * 16 + l15;
        float bv = bias[cg];
#pragma unroll
        for (int mi = 0; mi < 4; ++mi)
#pragma unroll
            for (int r = 0; r < 4; ++r) {
                int rg = m0 + wm + mi * 16 + quad * 4 + r;
                out[(size_t)rg * 768 + cg] = acc[mi][nj][r] + bv;
            }
    }
}

// ------ Flash attention, causal, LDS-STAGED K/V, 4-wave block, PIPELINED ----
// R7: R0-R6 showed every wave-private K/V fetch variant pins at ~2900+ cyc
// per wave-iter = per-CU L1/TA delivery wall (~30-64 B/cyc) + exposed L2
// latency; sharing/balance/intensity tweaks never reduced per-CU global
// traffic. Fix the root: stage K/V tiles in LDS ONCE PER BLOCK
// (global_load_lds) and let 4 waves consume from LDS (128 B/cyc pipe,
// global K/V traffic /4). Block = 4 waves x 32 q-rows; grid 24 bh x 32
// q-groups = 768, longest first, id%8 = bh%8 XCD-local.
// Stage schedule keeps the one-iteration-skew P pipeline: K staged 2 tiles
// ahead, V 1 ahead. Iter kt: stage K(kt+2)->Kb[kt&1], V(kt+1)->Vb[(kt&1)^1];
// PV(kt) from Vb[kt&1] + P(kt); QK(kt+1) from Kb[(kt&1)^1] -> P(kt+1);
// __syncthreads (drains vmcnt) lands the stages for iter kt+1 -> stage
// latency hides under a full iteration of MFMA.
// Per-wave causal limits: wave w needs nw = (qi>>1)+1 tiles of the block's
// nkt = 2gi+2; waves 0/1 skip their final (fully-masked) tile via
// wave-uniform guards; barriers/stages unconditional.
// LDS: Kb 16K + Vb 16K + P 34.8K = 67.6KB -> 2 blocks/CU (8 waves).
// Staged K/V reads are contiguous 16B/lane (2-way bank alias = free, m136).
// LDP=68 P rows: conflict-free (measured 0).
#define LDP 68

__global__ __launch_bounds__(256) void k_attn(
    const unsigned short* __restrict__ QL, const unsigned short* __restrict__ KL,
    const unsigned short* __restrict__ VL, unsigned short* __restrict__ Y)
{
    __shared__ __align__(16) unsigned short Kb[2 * 4096];      // 16384 B
    __shared__ __align__(16) unsigned short Vb[2 * 4096];      // 16384 B
    __shared__ __align__(16) unsigned short Ps[4 * 2 * 32 * LDP]; // 34816 B

    const int tid = threadIdx.x, lane = tid & 63;
    const int w = __builtin_amdgcn_readfirstlane(tid >> 6);   // wave id 0..3
    const int l15 = lane & 15, quad = lane >> 4;
    const int id = blockIdx.x;
    const int bh = id % 24;                   // id%8 = bh%8 -> XCD-local K/V
    const int gi = 31 - id / 24;              // longest first, gi in [0,32)
    const int qi = 4 * gi + w;                // this wave's 32-row q-tile
    const int q0 = qi * 32;
    const int nkt = 2 * gi + 2;               // block's key tiles
    const int ktd = qi >> 1;                  // wave's diagonal tile
    const int nw  = ktd + 1;                  // tiles this wave needs
    unsigned short* Pw = Ps + w * (2 * 32 * LDP);

    const int pw_off = l15 * LDP + quad * 4;  // P write base (shorts)
    const int pr_off = l15 * LDP + quad * 8;  // P read base

    const unsigned short* Qb = QL + (((size_t)bh * 128 + qi) * 4) * 512 + lane * 8;
    const unsigned short* Kg = KL + ((size_t)bh * 64) * 4096;  // + t*4096
    const unsigned short* Vg = VL + ((size_t)bh * 64) * 4096;

    // Q^T B-fragments
    bf16x8 qt[2][2];
#pragma unroll
    for (int m = 0; m < 2; ++m)
#pragma unroll
        for (int h = 0; h < 2; ++h)
            qt[m][h] = *(const bf16x8*)(Qb + (m * 2 + h) * 512);

    const f32x4 zero = {0.f, 0.f, 0.f, 0.f};
    f32x4 O[2][4], lac[2];
#pragma unroll
    for (int m = 0; m < 2; ++m) {
        lac[m] = zero;
#pragma unroll
        for (int dj = 0; dj < 4; ++dj) O[m][dj] = zero;
    }
    const short ONE = (short)0x3F80;  // bf16 1.0
    const bf16x8 onesf = {ONE, ONE, ONE, ONE, ONE, ONE, ONE, ONE};

    // ---- prologue staging: K(0)->Kb[0], K(1)->Kb[1], V(0)->Vb[0]
    gld_lds16(Kg + tid * 8,            Kb + tid * 8);
    gld_lds16(Kg + 2048 + tid * 8,     Kb + 2048 + tid * 8);
    gld_lds16(Kg + 4096 + tid * 8,     Kb + 4096 + tid * 8);
    gld_lds16(Kg + 6144 + tid * 8,     Kb + 6144 + tid * 8);
    gld_lds16(Vg + tid * 8,            Vb + tid * 8);
    gld_lds16(Vg + 2048 + tid * 8,     Vb + 2048 + tid * 8);
    __syncthreads();                         // stages landed

    // ---- prologue QK(0): read K(0) frags, then free Kb[0] for iter0's stage
    {
        bf16x8 ka[4][2];
#pragma unroll
        for (int i = 0; i < 4; ++i)
#pragma unroll
            for (int h = 0; h < 2; ++h)
                ka[i][h] = *(const bf16x8*)(Kb + (i * 2 + h) * 512 + lane * 8);
        __syncthreads();                     // all waves done reading Kb[0]

        f32x4 st[2][4];
#pragma unroll
        for (int i = 0; i < 4; ++i)
#pragma unroll
            for (int m = 0; m < 2; ++m) {
                f32x4 z = __builtin_amdgcn_mfma_f32_16x16x32_bf16(ka[i][0], qt[m][0], zero, 0, 0, 0);
                st[m][i] = __builtin_amdgcn_mfma_f32_16x16x32_bf16(ka[i][1], qt[m][1], z, 0, 0, 0);
            }
        if (ktd == 0) {                      // diagonal is tile 0
#pragma unroll
            for (int m = 0; m < 2; ++m)
#pragma unroll
                for (int i = 0; i < 4; ++i)
#pragma unroll
                    for (int r = 0; r < 4; ++r)
                        if (i * 16 + quad * 4 + r > q0 + m * 16 + l15)
                            st[m][i][r] = -INFINITY;
        }
#pragma unroll
        for (int m = 0; m < 2; ++m)
#pragma unroll
            for (int i = 0; i < 4; ++i) {
                unsigned e0 = __float_as_uint(__builtin_amdgcn_exp2f(st[m][i][0])) + 0x8000u;
                unsigned e1 = __float_as_uint(__builtin_amdgcn_exp2f(st[m][i][1])) + 0x8000u;
                unsigned e2 = __float_as_uint(__builtin_amdgcn_exp2f(st[m][i][2])) + 0x8000u;
                unsigned e3 = __float_as_uint(__builtin_amdgcn_exp2f(st[m][i][3])) + 0x8000u;
                uint2 pk;
                pk.x = __builtin_amdgcn_perm(e1, e0, 0x07060302);
                pk.y = __builtin_amdgcn_perm(e3, e2, 0x07060302);
                *(uint2*)(Pw + pw_off + m * 16 * LDP + i * 16) = pk;   // P(0)->buf0
            }
    }

    for (int kt = 0; kt < nkt; ++kt) {
        const int cur = kt & 1;

        // ---- stage next tiles (async; land at this iter's end barrier)
        if (kt + 2 < nkt) {                  // K(kt+2) -> Kb[cur]
            const unsigned short* s = Kg + (size_t)(kt + 2) * 4096;
            unsigned short* d = Kb + cur * 4096;
            gld_lds16(s + tid * 8, d + tid * 8);
            gld_lds16(s + 2048 + tid * 8, d + 2048 + tid * 8);
        }
        if (kt + 1 < nkt) {                  // V(kt+1) -> Vb[cur^1]
            const unsigned short* s = Vg + (size_t)(kt + 1) * 4096;
            unsigned short* d = Vb + (cur ^ 1) * 4096;
            gld_lds16(s + tid * 8, d + tid * 8);
            gld_lds16(s + 2048 + tid * 8, d + 2048 + tid * 8);
        }

        // ---- PV(kt): P(kt) from Pbuf[cur], V(kt) from Vb[cur]
        if (kt < nw) {
            const unsigned short* bc = Pw + cur * 32 * LDP;
            bf16x8 pa[2][2];
#pragma unroll
            for (int m = 0; m < 2; ++m) {
                pa[m][0] = *(const bf16x8*)(bc + pr_off + m * 16 * LDP);
                pa[m][1] = *(const bf16x8*)(bc + pr_off + m * 16 * LDP + 32);
            }
            bf16x8 vf[4][2];
#pragma unroll
            for (int dj = 0; dj < 4; ++dj)
#pragma unroll
                for (int h = 0; h < 2; ++h)
                    vf[dj][h] = *(const bf16x8*)(Vb + cur * 4096 + (dj * 2 + h) * 512 + lane * 8);

            __builtin_amdgcn_s_setprio(1);
#pragma unroll
            for (int m = 0; m < 2; ++m) {
                f32x4 z = __builtin_amdgcn_mfma_f32_16x16x32_bf16(pa[m][0], onesf, lac[m], 0, 0, 0);
                lac[m] = __builtin_amdgcn_mfma_f32_16x16x32_bf16(pa[m][1], onesf, z, 0, 0, 0);
            }
#pragma unroll
            for (int dj = 0; dj < 4; ++dj)
#pragma unroll
                for (int m = 0; m < 2; ++m) {
                    f32x4 y = __builtin_amdgcn_mfma_f32_16x16x32_bf16(pa[m][0], vf[dj][0], O[m][dj], 0, 0, 0);
                    O[m][dj] = __builtin_amdgcn_mfma_f32_16x16x32_bf16(pa[m][1], vf[dj][1], y, 0, 0, 0);
                }
            __builtin_amdgcn_s_setprio(0);
        }

        // ---- QK(kt+1): K(kt+1) from Kb[cur^1] -> P(kt+1) -> Pbuf[cur^1]
        if (kt + 1 < nw) {
            bf16x8 ka[4][2];
#pragma unroll
            for (int i = 0; i < 4; ++i)
#pragma unroll
                for (int h = 0; h < 2; ++h)
                    ka[i][h] = *(const bf16x8*)(Kb + (cur ^ 1) * 4096 + (i * 2 + h) * 512 + lane * 8);

            __builtin_amdgcn_s_setprio(1);
            f32x4 st[2][4];
#pragma unroll
            for (int i = 0; i < 4; ++i)
#pragma unroll
                for (int m = 0; m < 2; ++m) {
                    f32x4 z = __builtin_amdgcn_mfma_f32_16x16x32_bf16(ka[i][0], qt[m][0], zero, 0, 0, 0);
                    st[m][i] = __builtin_amdgcn_mfma_f32_16x16x32_bf16(ka[i][1], qt[m][1], z, 0, 0, 0);
                }
            __builtin_amdgcn_s_setprio(0);
            if (kt + 1 == ktd) {             // wave's diagonal tile
                const int kb = (kt + 1) * 64;
#pragma unroll
                for (int m = 0; m < 2; ++m)
#pragma unroll
                    for (int i = 0; i < 4; ++i)
#pragma unroll
                        for (int r = 0; r < 4; ++r)
                            if (kb + i * 16 + quad * 4 + r > q0 + m * 16 + l15)
                                st[m][i][r] = -INFINITY;
            }
            unsigned short* bn = Pw + (cur ^ 1) * 32 * LDP;
#pragma unroll
            for (int m = 0; m < 2; ++m)
#pragma unroll
                for (int i = 0; i < 4; ++i) {
                    unsigned e0 = __float_as_uint(__builtin_amdgcn_exp2f(st[m][i][0])) + 0x8000u;
                    unsigned e1 = __float_as_uint(__builtin_amdgcn_exp2f(st[m][i][1])) + 0x8000u;
                    unsigned e2 = __float_as_uint(__builtin_amdgcn_exp2f(st[m][i][2])) + 0x8000u;
                    unsigned e3 = __float_as_uint(__builtin_amdgcn_exp2f(st[m][i][3])) + 0x8000u;
                    uint2 pk;
                    pk.x = __builtin_amdgcn_perm(e1, e0, 0x07060302);
                    pk.y = __builtin_amdgcn_perm(e3, e2, 0x07060302);
                    *(uint2*)(bn + pw_off + m * 16 * LDP + i * 16) = pk;
                }
        }

        __syncthreads();   // drains vmcnt: staged K(kt+2)/V(kt+1) landed
    }

    // ---- epilogue: each wave owns its 32 rows -> O / l -> Y bf16
    const int b = bh / 12, hd = bh % 12;
#pragma unroll
    for (int m = 0; m < 2; ++m)
#pragma unroll
        for (int r = 0; r < 4; ++r) {
            float inv = 1.0f / lac[m][r];
            int t = q0 + 16 * m + quad * 4 + r;
            size_t base = ((size_t)(b * 4096 + t)) * 768 + hd * 64;
#pragma unroll
            for (int dj = 0; dj < 4; ++dj)
                Y[base + dj * 16 + l15] = f2bf(O[m][dj][r] * inv);
        }
}

// ---------------- launch ----------------
extern "C" void kernel_launch(void* const* d_in, const int* in_sizes, int n_in,
                              void* d_out, int out_size, void* d_ws, size_t ws_size,
                              hipStream_t stream) {
    (void)in_sizes; (void)n_in; (void)out_size; (void)ws_size;
    const float* x     = (const float*)d_in[0];
    const float* Wqkv  = (const float*)d_in[1];
    const float* bqkv  = (const float*)d_in[2];
    const float* Wproj = (const float*)d_in[3];
    const float* bproj = (const float*)d_in[4];
    float* out = (float*)d_out;

    char* ws = (char*)d_ws;
    size_t off = 0;
    auto alloc = [&](size_t bytes) -> void* {
        void* p = ws + off;
        off += (bytes + 255) & ~(size_t)255;
        return p;
    };
    unsigned short* xb     = (unsigned short*)alloc((size_t)8192 * 768 * 2);
    unsigned short* WqkvT  = (unsigned short*)alloc((size_t)2304 * 768 * 2);
    unsigned short* WprojT = (unsigned short*)alloc((size_t)768 * 768 * 2);
    unsigned short* QLb    = (unsigned short*)alloc((size_t)24 * 4096 * 64 * 2);
    unsigned short* KLb    = (unsigned short*)alloc((size_t)24 * 4096 * 64 * 2);
    unsigned short* VLb    = (unsigned short*)alloc((size_t)24 * 4096 * 64 * 2);
    unsigned short* Yb     = (unsigned short*)alloc((size_t)8192 * 768 * 2);

    k_convert<<<6144, 256, 0, stream>>>(x, xb, 8192 * 768 / 4);
    dim3 tb(32, 8);
    k_transpose<<<dim3(72, 24), tb, 0, stream>>>(Wqkv, WqkvT, 768, 2304);
    k_transpose<<<dim3(24, 24), tb, 0, stream>>>(Wproj, WprojT, 768, 768);
    k_gemm_qkv<<<dim3(64, 18), 256, 0, stream>>>(xb, WqkvT, bqkv, QLb, KLb, VLb);
    k_attn<<<dim3(768), 256, 0, stream>>>(QLb, KLb, VLb, Yb);
    k_gemm_proj<<<dim3(64, 6), 256, 0, stream>>>(Yb, WprojT, bproj, out);
}

// Round 8
// 263.959 us; speedup vs baseline: 1.0920x; 1.0920x over previous
//
#include <hip/hip_runtime.h>
#include <math.h>
#include <stdint.h>

// MFMA fragment types (guide §3, compile-verified on gfx950)
typedef __attribute__((ext_vector_type(8))) short bf16x8;   // 8 bf16 in 4 VGPRs
typedef __attribute__((ext_vector_type(4))) float f32x4;    // 4 fp32 acc

__device__ __forceinline__ unsigned short f2bf(float f) {
    union { float f; unsigned u; } v; v.f = f;
    return (unsigned short)((v.u + 0x7fffu + ((v.u >> 16) & 1u)) >> 16); // RNE
}

// async global->LDS, 16B per lane; LDS dest = firstlane base + lane*16 (m97)
__device__ __forceinline__ void gld_lds16(const void* g, void* l) {
    __builtin_amdgcn_global_load_lds(
        (const __attribute__((address_space(1))) unsigned*)(uintptr_t)g,
        (__attribute__((address_space(3))) unsigned*)(uintptr_t)l, 16, 0, 0);
}

// ---------------- fp32 -> bf16 elementwise (x4 vectorized) ----------------
__global__ void k_convert(const float* __restrict__ in, unsigned short* __restrict__ out, int n4) {
    int i = blockIdx.x * blockDim.x + threadIdx.x;
    if (i >= n4) return;
    float4 f = ((const float4*)in)[i];
    ushort4 o;
    o.x = f2bf(f.x); o.y = f2bf(f.y); o.z = f2bf(f.z); o.w = f2bf(f.w);
    ((ushort4*)out)[i] = o;
}

// ---------------- fp32 [R][C] -> bf16 [C][R] (tiled transpose) ----------------
__global__ void k_transpose(const float* __restrict__ in, unsigned short* __restrict__ out, int R, int C) {
    __shared__ float tile[32][33];
    int c0 = blockIdx.x * 32, r0 = blockIdx.y * 32;
    int tx = threadIdx.x, ty = threadIdx.y; // block (32,8)
#pragma unroll
    for (int i = 0; i < 4; ++i)
        tile[ty + i * 8][tx] = in[(size_t)(r0 + ty + i * 8) * C + c0 + tx];
    __syncthreads();
#pragma unroll
    for (int i = 0; i < 4; ++i)
        out[(size_t)(c0 + ty + i * 8) * R + r0 + tx] = f2bf(tile[tx][ty + i * 8]);
}

// ---------------- 128x128 bf16 MFMA GEMM core (m97-style staging) ----------
#define LDT 32

__device__ __forceinline__ void gemm_core(
    const unsigned short* __restrict__ A, const unsigned short* __restrict__ Bt,
    int K, unsigned short* As, unsigned short* Bs, f32x4 (&acc)[4][4])
{
    const int tid  = threadIdx.x;
    const int lane = tid & 63;
    const int w    = tid >> 6;
    const int wm   = (w >> 1) * 64, wn = (w & 1) * 64;
    const int l15  = lane & 15, quad = lane >> 4;
    const int m0 = blockIdx.x * 128, n0 = blockIdx.y * 128;

    const f32x4 zero = {0.f, 0.f, 0.f, 0.f};
#pragma unroll
    for (int i = 0; i < 4; ++i)
#pragma unroll
        for (int j = 0; j < 4; ++j) acc[i][j] = zero;

    const int r0 = tid >> 2, p8 = (tid & 3) * 8;
    const unsigned short* Ag0 = A  + (size_t)(m0 + r0) * K + p8;
    const unsigned short* Ag1 = A  + (size_t)(m0 + r0 + 64) * K + p8;
    const unsigned short* Bg0 = Bt + (size_t)(n0 + r0) * K + p8;
    const unsigned short* Bg1 = Bt + (size_t)(n0 + r0 + 64) * K + p8;
    unsigned short* lA0 = As + r0 * LDT + p8;          // byte offset tid*16
    unsigned short* lA1 = lA0 + 64 * LDT;
    unsigned short* lB0 = Bs + r0 * LDT + p8;
    unsigned short* lB1 = lB0 + 64 * LDT;

    const int nk = K >> 5;
    for (int kt = 0; kt < nk; ++kt) {
        __syncthreads();                    // LDS free (prev compute done)
        gld_lds16(Ag0, lA0);
        gld_lds16(Ag1, lA1);
        gld_lds16(Bg0, lB0);
        gld_lds16(Bg1, lB1);
        Ag0 += 32; Ag1 += 32; Bg0 += 32; Bg1 += 32;
        __syncthreads();                    // drains vmcnt -> data landed
        bf16x8 af[4], bfr[4];
#pragma unroll
        for (int mi = 0; mi < 4; ++mi)
            af[mi] = *(const bf16x8*)&As[(wm + mi * 16 + l15) * LDT + quad * 8];
#pragma unroll
        for (int nj = 0; nj < 4; ++nj)
            bfr[nj] = *(const bf16x8*)&Bs[(wn + nj * 16 + l15) * LDT + quad * 8];
#pragma unroll
        for (int mi = 0; mi < 4; ++mi)
#pragma unroll
            for (int nj = 0; nj < 4; ++nj)
                acc[mi][nj] = __builtin_amdgcn_mfma_f32_16x16x32_bf16(af[mi], bfr[nj], acc[mi][nj], 0, 0, 0);
    }
}

// QKV GEMM epilogue scatters into FRAGMENT-ORDER buffers so every attention
// global load is one coalesced 1024B block (base + lane*16B):
//  QL[bh][qi][m][h][lane][8]  : lane(l15,quad) holds Q[qi*32+16m+l15][32h+8quad+j]
//  KL[bh][t ][i][h][lane][8]  : lane holds K[64t+16i+l15][32h+8quad+j]
//  VL[bh][t ][dj][h][lane][8] : lane holds V[64t+32h+8quad+j][16dj+l15]
// Q pre-scaled by (1/8)*log2(e): softmax runs in exp2 domain.
__global__ __launch_bounds__(256) void k_gemm_qkv(
    const unsigned short* __restrict__ A, const unsigned short* __restrict__ Bt,
    const float* __restrict__ bias,
    unsigned short* __restrict__ QL, unsigned short* __restrict__ KL,
    unsigned short* __restrict__ VL)
{
    __shared__ __align__(16) unsigned short As[128 * LDT];
    __shared__ __align__(16) unsigned short Bs[128 * LDT];
    f32x4 acc[4][4];
    gemm_core(A, Bt, 768, As, Bs, acc);

    const int tid = threadIdx.x, lane = tid & 63, w = tid >> 6;
    const int wm = (w >> 1) * 64, wn = (w & 1) * 64;
    const int l15 = lane & 15, quad = lane >> 4;
    const int m0 = blockIdx.x * 128, n0 = blockIdx.y * 128;
    const float cscale = 0.18033688011f;  // (1/8) * log2(e)
#pragma unroll
    for (int nj = 0; nj < 4; ++nj) {
        int cg = n0 + wn + nj * 16 + l15;        // column in [0,2304)
        float bv = bias[cg];
        int which = cg / 768;                    // 0=q 1=k 2=v
        int rem = cg - which * 768;
        int hd = rem >> 6, d = rem & 63;
        float sc = (which == 0) ? cscale : 1.0f;
#pragma unroll
        for (int mi = 0; mi < 4; ++mi) {
#pragma unroll
            for (int r = 0; r < 4; ++r) {
                int rg = m0 + wm + mi * 16 + quad * 4 + r;   // row in [0,8192)
                int b = rg >> 12, tk = rg & 4095;
                int bh = b * 12 + hd;
                unsigned short ob = f2bf((acc[mi][nj][r] + bv) * sc);
                if (which == 0) {
                    size_t idx = ((((size_t)bh * 128 + (tk >> 5)) * 2 + ((tk >> 4) & 1)) * 2 + (d >> 5)) * 512
                               + ((d >> 3) & 3) * 128 + (tk & 15) * 8 + (d & 7);
                    QL[idx] = ob;
                } else if (which == 1) {
                    size_t idx = ((((size_t)bh * 64 + (tk >> 6)) * 4 + ((tk >> 4) & 3)) * 2 + (d >> 5)) * 512
                               + ((d >> 3) & 3) * 128 + (tk & 15) * 8 + (d & 7);
                    KL[idx] = ob;
                } else {
                    int wi = tk & 63;
                    size_t idx = ((((size_t)bh * 64 + (tk >> 6)) * 4 + (d >> 4)) * 2 + (wi >> 5)) * 512
                               + ((wi >> 3) & 3) * 128 + (d & 15) * 8 + (wi & 7);
                    VL[idx] = ob;
                }
            }
        }
    }
}

// Proj GEMM: A = y bf16 [8192][768], Bt = WprojT [768][768], out fp32 + bias
__global__ __launch_bounds__(256) void k_gemm_proj(
    const unsigned short* __restrict__ A, const unsigned short* __restrict__ Bt,
    const float* __restrict__ bias, float* __restrict__ out)
{
    __shared__ __align__(16) unsigned short As[128 * LDT];
    __shared__ __align__(16) unsigned short Bs[128 * LDT];
    f32x4 acc[4][4];
    gemm_core(A, Bt, 768, As, Bs, acc);

    const int tid = threadIdx.x, lane = tid & 63, w = tid >> 6;
    const int wm = (w >> 1) * 64, wn = (w & 1) * 64;
    const int l15 = lane & 15, quad = lane >> 4;
    const int m0 = blockIdx.x * 128, n0 = blockIdx.y * 128;
#pragma unroll
    for (int nj = 0; nj < 4; ++nj) {
        int cg = n0 + wn + nj * 16 + l15;
        float bv = bias[cg];
#pragma unroll
        for (int mi = 0; mi < 4; ++mi)
#pragma unroll
            for (int r = 0; r < 4; ++r) {
                int rg = m0 + wm + mi * 16 + quad * 4 + r;
                out[(size_t)rg * 768 + cg] = acc[mi][nj][r] + bv;
            }
    }
}

// ---- Flash attention, causal, SPLIT-PAIR BALANCED, XCD-local, PIPELINED ----
// R9: R4 (best, 88us) showed instantaneous throughput is fine at >=3 waves/
// SIMD but occupancy decays (blocks 1..64 iters all resident at t=0; time-avg
// 5.4 waves/CU). R5/R6 sustained occupancy but starved wave count. This
// round: R4's free-running structure and full 3072 waves, EVERY wave 32-33
// iters by construction. Pair q-tiles {p, 127-p}: s + nl = 64-65 tiles.
// Block = 2 waves: wave A = short tile p fully (owns output) + long-tile
// prefix [0,cA); wave B = long-tile suffix [cA,nl) incl. diagonal;
// cA = (nl-s)/2 -> A,B = 32-33 iters for ALL 1536 blocks. One end-of-kernel
// LDS combine (R3 pattern, 2 barriers) merges the long tile partials.
// 12 waves/CU sustained start-to-finish, no drain tail.
// grid id = p*24 + bh; id%8 = bh%8 -> XCD-local K/V (3 heads/XCD, 3MB < L2).
// Per-phase software pipeline (one-iteration skew, P dbuf in LDS) as R4.
// LDP=68 (136B rows): conflict-free (measured 0).
#define LDP 68

__device__ __forceinline__ void attn_phase(
    const unsigned short* __restrict__ Kbase,   // KL + bh*64*4096 + lane*8
    const unsigned short* __restrict__ Vbase,
    const bf16x8 (&qt)[2][2],
    int t0, int t1, int ktd, int q0,            // tiles [t0,t1); mask tile ktd (-1 = none)
    int l15, int quad,
    unsigned short* Pw, int pw_off, int pr_off,
    f32x4 (&O)[2][4], f32x4 (&lac)[2])
{
    const f32x4 zero = {0.f, 0.f, 0.f, 0.f};
    const short ONE = (short)0x3F80;  // bf16 1.0
    const bf16x8 onesf = {ONE, ONE, ONE, ONE, ONE, ONE, ONE, ONE};

    const unsigned short* kp = Kbase + (size_t)t0 * 4096;
    const unsigned short* vp = Vbase + (size_t)t0 * 4096;

    bf16x8 ka[4][2], vf[4][2];
#pragma unroll
    for (int i = 0; i < 4; ++i)
#pragma unroll
        for (int h = 0; h < 2; ++h)
            ka[i][h] = *(const bf16x8*)(kp + (i * 2 + h) * 512);
#pragma unroll
    for (int dj = 0; dj < 4; ++dj)
#pragma unroll
        for (int h = 0; h < 2; ++h)
            vf[dj][h] = *(const bf16x8*)(vp + (dj * 2 + h) * 512);

    // ---- prologue: st(t0) -> exp2 -> P buf0
    {
        f32x4 st[2][4];
#pragma unroll
        for (int i = 0; i < 4; ++i)
#pragma unroll
            for (int m = 0; m < 2; ++m) {
                f32x4 z = __builtin_amdgcn_mfma_f32_16x16x32_bf16(ka[i][0], qt[m][0], zero, 0, 0, 0);
                st[m][i] = __builtin_amdgcn_mfma_f32_16x16x32_bf16(ka[i][1], qt[m][1], z, 0, 0, 0);
            }
        if (t0 == ktd) {
            const int kb = t0 * 64;
#pragma unroll
            for (int m = 0; m < 2; ++m)
#pragma unroll
                for (int i = 0; i < 4; ++i)
#pragma unroll
                    for (int r = 0; r < 4; ++r)
                        if (kb + i * 16 + quad * 4 + r > q0 + m * 16 + l15)
                            st[m][i][r] = -INFINITY;
        }
#pragma unroll
        for (int m = 0; m < 2; ++m)
#pragma unroll
            for (int i = 0; i < 4; ++i) {
                unsigned e0 = __float_as_uint(__builtin_amdgcn_exp2f(st[m][i][0])) + 0x8000u;
                unsigned e1 = __float_as_uint(__builtin_amdgcn_exp2f(st[m][i][1])) + 0x8000u;
                unsigned e2 = __float_as_uint(__builtin_amdgcn_exp2f(st[m][i][2])) + 0x8000u;
                unsigned e3 = __float_as_uint(__builtin_amdgcn_exp2f(st[m][i][3])) + 0x8000u;
                uint2 pk;
                pk.x = __builtin_amdgcn_perm(e1, e0, 0x07060302);
                pk.y = __builtin_amdgcn_perm(e3, e2, 0x07060302);
                *(uint2*)(Pw + pw_off + m * 16 * LDP + i * 16) = pk;
            }
    }

    for (int kt = t0; kt < t1; ++kt) {
        unsigned short* bc = Pw + ((kt - t0) & 1) * 32 * LDP;
        unsigned short* bn = Pw + (((kt - t0) & 1) ^ 1) * 32 * LDP;
        const bool more = (kt + 1 < t1);

        // ---- read P(kt) as A-frags (written last iter; no RAW stall)
        bf16x8 pa[2][2];
#pragma unroll
        for (int m = 0; m < 2; ++m) {
            pa[m][0] = *(const bf16x8*)(bc + pr_off + m * 16 * LDP);
            pa[m][1] = *(const bf16x8*)(bc + pr_off + m * 16 * LDP + 32);
        }

        // ---- issue ka(kt+1) early; latency covered by l/O MFMAs below
        if (more) {
            kp += 4096;
#pragma unroll
            for (int i = 0; i < 4; ++i)
#pragma unroll
                for (int h = 0; h < 2; ++h)
                    ka[i][h] = *(const bf16x8*)(kp + (i * 2 + h) * 512);
        }

        // ---- l += P @ ones ; O += P V(kt)   [T5: prio up in MFMA cluster]
        __builtin_amdgcn_s_setprio(1);
#pragma unroll
        for (int m = 0; m < 2; ++m) {
            f32x4 z = __builtin_amdgcn_mfma_f32_16x16x32_bf16(pa[m][0], onesf, lac[m], 0, 0, 0);
            lac[m] = __builtin_amdgcn_mfma_f32_16x16x32_bf16(pa[m][1], onesf, z, 0, 0, 0);
        }
#pragma unroll
        for (int dj = 0; dj < 4; ++dj)
#pragma unroll
            for (int m = 0; m < 2; ++m) {
                f32x4 y = __builtin_amdgcn_mfma_f32_16x16x32_bf16(pa[m][0], vf[dj][0], O[m][dj], 0, 0, 0);
                O[m][dj] = __builtin_amdgcn_mfma_f32_16x16x32_bf16(pa[m][1], vf[dj][1], y, 0, 0, 0);
            }
        __builtin_amdgcn_s_setprio(0);

        if (more) {
            // ---- issue vf(kt+1); latency covered by QK + exp2 below
            vp += 4096;
#pragma unroll
            for (int dj = 0; dj < 4; ++dj)
#pragma unroll
                for (int h = 0; h < 2; ++h)
                    vf[dj][h] = *(const bf16x8*)(vp + (dj * 2 + h) * 512);

            // ---- st(kt+1) = K Q^T (ka latency already covered)
            __builtin_amdgcn_s_setprio(1);
            f32x4 st[2][4];
#pragma unroll
            for (int i = 0; i < 4; ++i)
#pragma unroll
                for (int m = 0; m < 2; ++m) {
                    f32x4 z = __builtin_amdgcn_mfma_f32_16x16x32_bf16(ka[i][0], qt[m][0], zero, 0, 0, 0);
                    st[m][i] = __builtin_amdgcn_mfma_f32_16x16x32_bf16(ka[i][1], qt[m][1], z, 0, 0, 0);
                }
            __builtin_amdgcn_s_setprio(0);
            if (kt + 1 == ktd) {
                const int kb = (kt + 1) * 64;
#pragma unroll
                for (int m = 0; m < 2; ++m)
#pragma unroll
                    for (int i = 0; i < 4; ++i)
#pragma unroll
                        for (int r = 0; r < 4; ++r)
                            if (kb + i * 16 + quad * 4 + r > q0 + m * 16 + l15)
                                st[m][i][r] = -INFINITY;
            }
            // ---- p = exp2(s); pack; write P(kt+1) to other buffer
#pragma unroll
            for (int m = 0; m < 2; ++m)
#pragma unroll
                for (int i = 0; i < 4; ++i) {
                    unsigned e0 = __float_as_uint(__builtin_amdgcn_exp2f(st[m][i][0])) + 0x8000u;
                    unsigned e1 = __float_as_uint(__builtin_amdgcn_exp2f(st[m][i][1])) + 0x8000u;
                    unsigned e2 = __float_as_uint(__builtin_amdgcn_exp2f(st[m][i][2])) + 0x8000u;
                    unsigned e3 = __float_as_uint(__builtin_amdgcn_exp2f(st[m][i][3])) + 0x8000u;
                    uint2 pk;
                    pk.x = __builtin_amdgcn_perm(e1, e0, 0x07060302);
                    pk.y = __builtin_amdgcn_perm(e3, e2, 0x07060302);
                    *(uint2*)(bn + pw_off + m * 16 * LDP + i * 16) = pk;
                }
        }
    }
}

__device__ __forceinline__ void attn_writeout(
    const f32x4 (&O)[2][4], const f32x4 (&lac)[2],
    int q0, int b, int hd, int quad, int l15, unsigned short* __restrict__ Y)
{
#pragma unroll
    for (int m = 0; m < 2; ++m)
#pragma unroll
        for (int r = 0; r < 4; ++r) {
            float inv = 1.0f / lac[m][r];
            int t = q0 + 16 * m + quad * 4 + r;
            size_t base = ((size_t)(b * 4096 + t)) * 768 + hd * 64;
#pragma unroll
            for (int dj = 0; dj < 4; ++dj)
                Y[base + dj * 16 + l15] = f2bf(O[m][dj][r] * inv);
        }
}

__global__ __launch_bounds__(128) void k_attn(
    const unsigned short* __restrict__ QL, const unsigned short* __restrict__ KL,
    const unsigned short* __restrict__ VL, unsigned short* __restrict__ Y)
{
    // P dbuf: 2 waves x 2 bufs x 32*LDP shorts = 17408B; combine buffer
    // (2560 floats = 10240B) has disjoint lifetime -> union.
    __shared__ __align__(16) char smem[17408];
    unsigned short* Ps = (unsigned short*)smem;
    float* Cb = (float*)smem;

    const int tid = threadIdx.x, lane = tid & 63;
    const int w = __builtin_amdgcn_readfirstlane(tid >> 6);   // wave-uniform 0..1
    const int l15 = lane & 15, quad = lane >> 4;
    const int id = blockIdx.x;
    const int bh = id % 24;                   // id%8 = bh%8 -> XCD-local K/V
    const int p  = id / 24;                   // pair index 0..63
    const int qs = p, ql = 127 - p;           // short / long q-tiles
    const int s  = p / 2 + 1;                 // short key tiles (1..32)
    const int nl = ql / 2 + 1;                // long key tiles (32..64)
    const int cA = (nl - s) / 2;              // A's long prefix; A=s+cA, B=nl-cA (32-33)
    unsigned short* Pw = Ps + w * 2 * 32 * LDP;

    const int pw_off = l15 * LDP + quad * 4;  // P write base (shorts)
    const int pr_off = l15 * LDP + quad * 8;  // P read base

    const unsigned short* Kbase = KL + ((size_t)bh * 64) * 4096 + lane * 8;
    const unsigned short* Vbase = VL + ((size_t)bh * 64) * 4096 + lane * 8;
    const int b = bh / 12, hd = bh % 12;

    const f32x4 zero = {0.f, 0.f, 0.f, 0.f};
    f32x4 O[2][4], lac[2];
    bf16x8 qt[2][2];

    if (w == 0) {
        // ---- wave A: short tile fully (owns its 32 rows)
        {
            const unsigned short* Qb = QL + (((size_t)bh * 128 + qs) * 4) * 512 + lane * 8;
#pragma unroll
            for (int m = 0; m < 2; ++m)
#pragma unroll
                for (int h = 0; h < 2; ++h)
                    qt[m][h] = *(const bf16x8*)(Qb + (m * 2 + h) * 512);
        }
#pragma unroll
        for (int m = 0; m < 2; ++m) {
            lac[m] = zero;
#pragma unroll
            for (int dj = 0; dj < 4; ++dj) O[m][dj] = zero;
        }
        attn_phase(Kbase, Vbase, qt, 0, s, s - 1, qs * 32, l15, quad,
                   Pw, pw_off, pr_off, O, lac);
        attn_writeout(O, lac, qs * 32, b, hd, quad, l15, Y);

        // ---- wave A: long-tile prefix [0, cA) (no diagonal in range)
        {
            const unsigned short* Qb = QL + (((size_t)bh * 128 + ql) * 4) * 512 + lane * 8;
#pragma unroll
            for (int m = 0; m < 2; ++m)
#pragma unroll
                for (int h = 0; h < 2; ++h)
                    qt[m][h] = *(const bf16x8*)(Qb + (m * 2 + h) * 512);
        }
#pragma unroll
        for (int m = 0; m < 2; ++m) {
            lac[m] = zero;
#pragma unroll
            for (int dj = 0; dj < 4; ++dj) O[m][dj] = zero;
        }
        if (cA > 0)
            attn_phase(Kbase, Vbase, qt, 0, cA, -1, ql * 32, l15, quad,
                       Pw, pw_off, pr_off, O, lac);
    } else {
        // ---- wave B: long-tile suffix [cA, nl) (includes diagonal nl-1)
        {
            const unsigned short* Qb = QL + (((size_t)bh * 128 + ql) * 4) * 512 + lane * 8;
#pragma unroll
            for (int m = 0; m < 2; ++m)
#pragma unroll
                for (int h = 0; h < 2; ++h)
                    qt[m][h] = *(const bf16x8*)(Qb + (m * 2 + h) * 512);
        }
#pragma unroll
        for (int m = 0; m < 2; ++m) {
            lac[m] = zero;
#pragma unroll
            for (int dj = 0; dj < 4; ++dj) O[m][dj] = zero;
        }
        attn_phase(Kbase, Vbase, qt, cA, nl, nl - 1, ql * 32, l15, quad,
                   Pw, pw_off, pr_off, O, lac);
    }

    // ---- combine long-tile partials (additive: no max used) via LDS
    __syncthreads();   // both waves done with their P regions
    if (w == 0) {
#pragma unroll
        for (int m = 0; m < 2; ++m) {
#pragma unroll
            for (int dj = 0; dj < 4; ++dj)
                *(f32x4*)&Cb[(m * 4 + dj) * 256 + lane * 4] = O[m][dj];
            *(f32x4*)&Cb[2048 + m * 256 + lane * 4] = lac[m];
        }
    }
    __syncthreads();
    if (w == 1) {
#pragma unroll
        for (int m = 0; m < 2; ++m) {
#pragma unroll
            for (int dj = 0; dj < 4; ++dj)
                O[m][dj] += *(const f32x4*)&Cb[(m * 4 + dj) * 256 + lane * 4];
            lac[m] += *(const f32x4*)&Cb[2048 + m * 256 + lane * 4];
        }
        attn_writeout(O, lac, ql * 32, b, hd, quad, l15, Y);
    }
}

// ---------------- launch ----------------
extern "C" void kernel_launch(void* const* d_in, const int* in_sizes, int n_in,
                              void* d_out, int out_size, void* d_ws, size_t ws_size,
                              hipStream_t stream) {
    (void)in_sizes; (void)n_in; (void)out_size; (void)ws_size;
    const float* x     = (const float*)d_in[0];
    const float* Wqkv  = (const float*)d_in[1];
    const float* bqkv  = (const float*)d_in[2];
    const float* Wproj = (const float*)d_in[3];
    const float* bproj = (const float*)d_in[4];
    float* out = (float*)d_out;

    char* ws = (char*)d_ws;
    size_t off = 0;
    auto alloc = [&](size_t bytes) -> void* {
        void* p = ws + off;
        off += (bytes + 255) & ~(size_t)255;
        return p;
    };
    unsigned short* xb     = (unsigned short*)alloc((size_t)8192 * 768 * 2);
    unsigned short* WqkvT  = (unsigned short*)alloc((size_t)2304 * 768 * 2);
    unsigned short* WprojT = (unsigned short*)alloc((size_t)768 * 768 * 2);
    unsigned short* QLb    = (unsigned short*)alloc((size_t)24 * 4096 * 64 * 2);
    unsigned short* KLb    = (unsigned short*)alloc((size_t)24 * 4096 * 64 * 2);
    unsigned short* VLb    = (unsigned short*)alloc((size_t)24 * 4096 * 64 * 2);
    unsigned short* Yb     = (unsigned short*)alloc((size_t)8192 * 768 * 2);

    k_convert<<<6144, 256, 0, stream>>>(x, xb, 8192 * 768 / 4);
    dim3 tb(32, 8);
    k_transpose<<<dim3(72, 24), tb, 0, stream>>>(Wqkv, WqkvT, 768, 2304);
    k_transpose<<<dim3(24, 24), tb, 0, stream>>>(Wproj, WprojT, 768, 768);
    k_gemm_qkv<<<dim3(64, 18), 256, 0, stream>>>(xb, WqkvT, bqkv, QLb, KLb, VLb);
    k_attn<<<dim3(1536), 128, 0, stream>>>(QLb, KLb, VLb, Yb);
    k_gemm_proj<<<dim3(64, 6), 256, 0, stream>>>(Yb, WprojT, bproj, out);
}

// Round 9
// 243.025 us; speedup vs baseline: 1.1860x; 1.0861x over previous
//
#include <hip/hip_runtime.h>
#include <math.h>
#include <stdint.h>

// MFMA fragment types (guide §3, compile-verified on gfx950)
typedef __attribute__((ext_vector_type(8))) short bf16x8;   // 8 bf16 in 4 VGPRs
typedef __attribute__((ext_vector_type(4))) float f32x4;    // 4 fp32 acc

__device__ __forceinline__ unsigned short f2bf(float f) {
    union { float f; unsigned u; } v; v.f = f;
    return (unsigned short)((v.u + 0x7fffu + ((v.u >> 16) & 1u)) >> 16); // RNE
}

// async global->LDS, 16B per lane; LDS dest = firstlane base + lane*16 (m97)
__device__ __forceinline__ void gld_lds16(const void* g, void* l) {
    __builtin_amdgcn_global_load_lds(
        (const __attribute__((address_space(1))) unsigned*)(uintptr_t)g,
        (__attribute__((address_space(3))) unsigned*)(uintptr_t)l, 16, 0, 0);
}

// ---------------- fp32 -> bf16 elementwise (x4 vectorized) ----------------
__global__ void k_convert(const float* __restrict__ in, unsigned short* __restrict__ out, int n4) {
    int i = blockIdx.x * blockDim.x + threadIdx.x;
    if (i >= n4) return;
    float4 f = ((const float4*)in)[i];
    ushort4 o;
    o.x = f2bf(f.x); o.y = f2bf(f.y); o.z = f2bf(f.z); o.w = f2bf(f.w);
    ((ushort4*)out)[i] = o;
}

// ---------------- fp32 [R][C] -> bf16 [C][R] (tiled transpose) ----------------
__global__ void k_transpose(const float* __restrict__ in, unsigned short* __restrict__ out, int R, int C) {
    __shared__ float tile[32][33];
    int c0 = blockIdx.x * 32, r0 = blockIdx.y * 32;
    int tx = threadIdx.x, ty = threadIdx.y; // block (32,8)
#pragma unroll
    for (int i = 0; i < 4; ++i)
        tile[ty + i * 8][tx] = in[(size_t)(r0 + ty + i * 8) * C + c0 + tx];
    __syncthreads();
#pragma unroll
    for (int i = 0; i < 4; ++i)
        out[(size_t)(c0 + ty + i * 8) * R + r0 + tx] = f2bf(tile[tx][ty + i * 8]);
}

// ---------------- 128x128 bf16 MFMA GEMM core (m97-style staging) ----------
#define LDT 32

__device__ __forceinline__ void gemm_core(
    const unsigned short* __restrict__ A, const unsigned short* __restrict__ Bt,
    int K, unsigned short* As, unsigned short* Bs, f32x4 (&acc)[4][4])
{
    const int tid  = threadIdx.x;
    const int lane = tid & 63;
    const int w    = tid >> 6;
    const int wm   = (w >> 1) * 64, wn = (w & 1) * 64;
    const int l15  = lane & 15, quad = lane >> 4;
    const int m0 = blockIdx.x * 128, n0 = blockIdx.y * 128;

    const f32x4 zero = {0.f, 0.f, 0.f, 0.f};
#pragma unroll
    for (int i = 0; i < 4; ++i)
#pragma unroll
        for (int j = 0; j < 4; ++j) acc[i][j] = zero;

    const int r0 = tid >> 2, p8 = (tid & 3) * 8;
    const unsigned short* Ag0 = A  + (size_t)(m0 + r0) * K + p8;
    const unsigned short* Ag1 = A  + (size_t)(m0 + r0 + 64) * K + p8;
    const unsigned short* Bg0 = Bt + (size_t)(n0 + r0) * K + p8;
    const unsigned short* Bg1 = Bt + (size_t)(n0 + r0 + 64) * K + p8;
    unsigned short* lA0 = As + r0 * LDT + p8;          // byte offset tid*16
    unsigned short* lA1 = lA0 + 64 * LDT;
    unsigned short* lB0 = Bs + r0 * LDT + p8;
    unsigned short* lB1 = lB0 + 64 * LDT;

    const int nk = K >> 5;
    for (int kt = 0; kt < nk; ++kt) {
        __syncthreads();                    // LDS free (prev compute done)
        gld_lds16(Ag0, lA0);
        gld_lds16(Ag1, lA1);
        gld_lds16(Bg0, lB0);
        gld_lds16(Bg1, lB1);
        Ag0 += 32; Ag1 += 32; Bg0 += 32; Bg1 += 32;
        __syncthreads();                    // drains vmcnt -> data landed
        bf16x8 af[4], bfr[4];
#pragma unroll
        for (int mi = 0; mi < 4; ++mi)
            af[mi] = *(const bf16x8*)&As[(wm + mi * 16 + l15) * LDT + quad * 8];
#pragma unroll
        for (int nj = 0; nj < 4; ++nj)
            bfr[nj] = *(const bf16x8*)&Bs[(wn + nj * 16 + l15) * LDT + quad * 8];
#pragma unroll
        for (int mi = 0; mi < 4; ++mi)
#pragma unroll
            for (int nj = 0; nj < 4; ++nj)
                acc[mi][nj] = __builtin_amdgcn_mfma_f32_16x16x32_bf16(af[mi], bfr[nj], acc[mi][nj], 0, 0, 0);
    }
}

// QKV GEMM epilogue scatters into FRAGMENT-ORDER buffers so every attention
// global load is one coalesced 1024B block (base + lane*16B):
//  QL[bh][qi][m][h][lane][8]  : lane(l15,quad) holds Q[qi*32+16m+l15][32h+8quad+j]
//  KL[bh][t ][i][h][lane][8]  : lane holds K[64t+16i+l15][32h+8quad+j]
//  VL[bh][t ][dj][h][lane][8] : lane holds V[64t+32h+8quad+j][16dj+l15]
// Q pre-scaled by (1/8)*log2(e): softmax runs in exp2 domain.
__global__ __launch_bounds__(256) void k_gemm_qkv(
    const unsigned short* __restrict__ A, const unsigned short* __restrict__ Bt,
    const float* __restrict__ bias,
    unsigned short* __restrict__ QL, unsigned short* __restrict__ KL,
    unsigned short* __restrict__ VL)
{
    __shared__ __align__(16) unsigned short As[128 * LDT];
    __shared__ __align__(16) unsigned short Bs[128 * LDT];
    f32x4 acc[4][4];
    gemm_core(A, Bt, 768, As, Bs, acc);

    const int tid = threadIdx.x, lane = tid & 63, w = tid >> 6;
    const int wm = (w >> 1) * 64, wn = (w & 1) * 64;
    const int l15 = lane & 15, quad = lane >> 4;
    const int m0 = blockIdx.x * 128, n0 = blockIdx.y * 128;
    const float cscale = 0.18033688011f;  // (1/8) * log2(e)
#pragma unroll
    for (int nj = 0; nj < 4; ++nj) {
        int cg = n0 + wn + nj * 16 + l15;        // column in [0,2304)
        float bv = bias[cg];
        int which = cg / 768;                    // 0=q 1=k 2=v
        int rem = cg - which * 768;
        int hd = rem >> 6, d = rem & 63;
        float sc = (which == 0) ? cscale : 1.0f;
#pragma unroll
        for (int mi = 0; mi < 4; ++mi) {
#pragma unroll
            for (int r = 0; r < 4; ++r) {
                int rg = m0 + wm + mi * 16 + quad * 4 + r;   // row in [0,8192)
                int b = rg >> 12, tk = rg & 4095;
                int bh = b * 12 + hd;
                unsigned short ob = f2bf((acc[mi][nj][r] + bv) * sc);
                if (which == 0) {
                    size_t idx = ((((size_t)bh * 128 + (tk >> 5)) * 2 + ((tk >> 4) & 1)) * 2 + (d >> 5)) * 512
                               + ((d >> 3) & 3) * 128 + (tk & 15) * 8 + (d & 7);
                    QL[idx] = ob;
                } else if (which == 1) {
                    size_t idx = ((((size_t)bh * 64 + (tk >> 6)) * 4 + ((tk >> 4) & 3)) * 2 + (d >> 5)) * 512
                               + ((d >> 3) & 3) * 128 + (tk & 15) * 8 + (d & 7);
                    KL[idx] = ob;
                } else {
                    int wi = tk & 63;
                    size_t idx = ((((size_t)bh * 64 + (tk >> 6)) * 4 + (d >> 4)) * 2 + (wi >> 5)) * 512
                               + ((wi >> 3) & 3) * 128 + (d & 15) * 8 + (wi & 7);
                    VL[idx] = ob;
                }
            }
        }
    }
}

// Proj GEMM: A = y bf16 [8192][768], Bt = WprojT [768][768], out fp32 + bias
__global__ __launch_bounds__(256) void k_gemm_proj(
    const unsigned short* __restrict__ A, const unsigned short* __restrict__ Bt,
    const float* __restrict__ bias, float* __restrict__ out)
{
    __shared__ __align__(16) unsigned short As[128 * LDT];
    __shared__ __align__(16) unsigned short Bs[128 * LDT];
    f32x4 acc[4][4];
    gemm_core(A, Bt, 768, As, Bs, acc);

    const int tid = threadIdx.x, lane = tid & 63, w = tid >> 6;
    const int wm = (w >> 1) * 64, wn = (w & 1) * 64;
    const int l15 = lane & 15, quad = lane >> 4;
    const int m0 = blockIdx.x * 128, n0 = blockIdx.y * 128;
#pragma unroll
    for (int nj = 0; nj < 4; ++nj) {
        int cg = n0 + wn + nj * 16 + l15;
        float bv = bias[cg];
#pragma unroll
        for (int mi = 0; mi < 4; ++mi)
#pragma unroll
            for (int r = 0; r < 4; ++r) {
                int rg = m0 + wm + mi * 16 + quad * 4 + r;
                out[(size_t)rg * 768 + cg] = acc[mi][nj][r] + bv;
            }
    }
}

// -- Flash attention, causal, PAIRED-Q, BALANCED MAP + WAVE PRIORITY --------
// R10 = R4 (best attn, 88.5us) + two zero-inner-loop-cost scheduling fixes:
// (1) COMPLEMENT MAPPING: j = id/24, g = j<32 ? j : 95-j. Same-CU 6-block
//     sets {p, p+256, ..., p+1280} have j-pairs at distance 32 -> g-pairs
//     {x, 63-x} -> per-CU work = 189+-2 block-iters, exactly constant
//     (monotone map was 161-227, +-17% -> straggler CUs set the makespan).
// (2) STATIC WAVE PRIORITY prio = g>>4 (0..3), set once at entry (s_setprio
//     is persistent wave state). CU scheduler issues critical-path (long)
//     waves first; short waves (2.5x slack) fill residual slots -> intra-CU
//     tail runs at the long wave's dep-limited rate, not fair-share.
//     Replaces the in-loop setprio toggle (would clobber the base prio).
// Everything else identical to R4: 2 waves/block on ADJACENT q-tiles
// {2g, 2g+1}, same key loop 0..g (identical length/addresses -> L1 sharing,
// no barrier), no combine, each wave owns its 32 rows. id%8 = bh%8 XCD-local
// K/V (3 heads/XCD, 3MB < 4MB L2). One-iteration-skew software pipeline,
// P dbuf in LDS, LDP=68 conflict-free.
#define LDP 68

__global__ __launch_bounds__(128) void k_attn(
    const unsigned short* __restrict__ QL, const unsigned short* __restrict__ KL,
    const unsigned short* __restrict__ VL, unsigned short* __restrict__ Y)
{
    // P dbuf: 2 waves x 2 bufs x 32*LDP shorts = 17408B (wave-private)
    __shared__ __align__(16) char smem[17408];
    unsigned short* Ps = (unsigned short*)smem;

    const int tid = threadIdx.x, lane = tid & 63;
    const int w = __builtin_amdgcn_readfirstlane(tid >> 6);   // wave-uniform, 0..1
    const int l15 = lane & 15, quad = lane >> 4;
    const int id = blockIdx.x;
    const int bh = id % 24;                   // id%8 = bh%8 -> XCD-local K/V
    const int j  = id / 24;                   // 0..63
    const int g  = (j < 32) ? j : 95 - j;     // complement map: per-CU work const
    const int qi = 2 * g + w;                 // this wave's 32-row q-tile
    const int q0 = qi * 32;
    const int nkt = g + 1;                    // key tiles; SAME for both waves
    unsigned short* Pw = Ps + w * 2 * 32 * LDP;   // this wave's two buffers

    // static priority: long (critical-path) waves issue first on their SIMD
    const int pr = g >> 4;
    if (pr == 3)      __builtin_amdgcn_s_setprio(3);
    else if (pr == 2) __builtin_amdgcn_s_setprio(2);
    else if (pr == 1) __builtin_amdgcn_s_setprio(1);

    const int pw_off = l15 * LDP + quad * 4;  // P write base (shorts)
    const int pr_off = l15 * LDP + quad * 8;  // P read base

    // fragment-chunk bases (each chunk = 512 shorts = 1024B, lane offset *8)
    const unsigned short* Qb = QL + (((size_t)bh * 128 + qi) * 4) * 512 + lane * 8;
    const unsigned short* kp = KL + ((size_t)bh * 64) * 4096 + lane * 8;
    const unsigned short* vp = VL + ((size_t)bh * 64) * 4096 + lane * 8;

    // Q^T B-fragments (chunk layout matches B-frag exactly)
    bf16x8 qt[2][2];
#pragma unroll
    for (int m = 0; m < 2; ++m)
#pragma unroll
        for (int h = 0; h < 2; ++h)
            qt[m][h] = *(const bf16x8*)(Qb + (m * 2 + h) * 512);

    const f32x4 zero = {0.f, 0.f, 0.f, 0.f};
    f32x4 O[2][4], lac[2];
#pragma unroll
    for (int m = 0; m < 2; ++m) {
        lac[m] = zero;
#pragma unroll
        for (int dj = 0; dj < 4; ++dj) O[m][dj] = zero;
    }

    const short ONE = (short)0x3F80;  // bf16 1.0
    const bf16x8 onesf = {ONE, ONE, ONE, ONE, ONE, ONE, ONE, ONE};

    bf16x8 ka[4][2], vf[4][2];
#pragma unroll
    for (int i = 0; i < 4; ++i)
#pragma unroll
        for (int h = 0; h < 2; ++h)
            ka[i][h] = *(const bf16x8*)(kp + (i * 2 + h) * 512);
#pragma unroll
    for (int dj = 0; dj < 4; ++dj)
#pragma unroll
        for (int h = 0; h < 2; ++h)
            vf[dj][h] = *(const bf16x8*)(vp + (dj * 2 + h) * 512);

    // ---- prologue: st(0) -> exp2 -> P buf0
    {
        f32x4 st[2][4];
#pragma unroll
        for (int i = 0; i < 4; ++i)
#pragma unroll
            for (int m = 0; m < 2; ++m) {
                f32x4 z = __builtin_amdgcn_mfma_f32_16x16x32_bf16(ka[i][0], qt[m][0], zero, 0, 0, 0);
                st[m][i] = __builtin_amdgcn_mfma_f32_16x16x32_bf16(ka[i][1], qt[m][1], z, 0, 0, 0);
            }
        if (nkt == 1) {                 // tile 0 is the diagonal tile
#pragma unroll
            for (int m = 0; m < 2; ++m)
#pragma unroll
                for (int i = 0; i < 4; ++i)
#pragma unroll
                    for (int r = 0; r < 4; ++r)
                        if (i * 16 + quad * 4 + r > q0 + m * 16 + l15)
                            st[m][i][r] = -INFINITY;
        }
#pragma unroll
        for (int m = 0; m < 2; ++m)
#pragma unroll
            for (int i = 0; i < 4; ++i) {
                unsigned e0 = __float_as_uint(__builtin_amdgcn_exp2f(st[m][i][0])) + 0x8000u;
                unsigned e1 = __float_as_uint(__builtin_amdgcn_exp2f(st[m][i][1])) + 0x8000u;
                unsigned e2 = __float_as_uint(__builtin_amdgcn_exp2f(st[m][i][2])) + 0x8000u;
                unsigned e3 = __float_as_uint(__builtin_amdgcn_exp2f(st[m][i][3])) + 0x8000u;
                uint2 pk;
                pk.x = __builtin_amdgcn_perm(e1, e0, 0x07060302);
                pk.y = __builtin_amdgcn_perm(e3, e2, 0x07060302);
                *(uint2*)(Pw + pw_off + m * 16 * LDP + i * 16) = pk;
            }
    }

    for (int kt = 0; kt < nkt; ++kt) {
        unsigned short* bc = Pw + (kt & 1) * 32 * LDP;
        unsigned short* bn = Pw + ((kt & 1) ^ 1) * 32 * LDP;
        const bool more = (kt + 1 < nkt);

        // ---- read P(kt) as A-frags (written last iter; no RAW stall)
        bf16x8 pa[2][2];
#pragma unroll
        for (int m = 0; m < 2; ++m) {
            pa[m][0] = *(const bf16x8*)(bc + pr_off + m * 16 * LDP);
            pa[m][1] = *(const bf16x8*)(bc + pr_off + m * 16 * LDP + 32);
        }

        // ---- issue ka(kt+1) early; latency covered by l/O MFMAs below
        if (more) {
            kp += 4096;
#pragma unroll
            for (int i = 0; i < 4; ++i)
#pragma unroll
                for (int h = 0; h < 2; ++h)
                    ka[i][h] = *(const bf16x8*)(kp + (i * 2 + h) * 512);
        }

        // ---- l += P @ ones ; O += P V(kt)
#pragma unroll
        for (int m = 0; m < 2; ++m) {
            f32x4 z = __builtin_amdgcn_mfma_f32_16x16x32_bf16(pa[m][0], onesf, lac[m], 0, 0, 0);
            lac[m] = __builtin_amdgcn_mfma_f32_16x16x32_bf16(pa[m][1], onesf, z, 0, 0, 0);
        }
#pragma unroll
        for (int dj = 0; dj < 4; ++dj)
#pragma unroll
            for (int m = 0; m < 2; ++m) {
                f32x4 y = __builtin_amdgcn_mfma_f32_16x16x32_bf16(pa[m][0], vf[dj][0], O[m][dj], 0, 0, 0);
                O[m][dj] = __builtin_amdgcn_mfma_f32_16x16x32_bf16(pa[m][1], vf[dj][1], y, 0, 0, 0);
            }

        if (more) {
            // ---- issue vf(kt+1); latency covered by QK + exp2 below
            vp += 4096;
#pragma unroll
            for (int dj = 0; dj < 4; ++dj)
#pragma unroll
                for (int h = 0; h < 2; ++h)
                    vf[dj][h] = *(const bf16x8*)(vp + (dj * 2 + h) * 512);

            // ---- st(kt+1) = K Q^T (ka latency already covered)
            f32x4 st[2][4];
#pragma unroll
            for (int i = 0; i < 4; ++i)
#pragma unroll
                for (int m = 0; m < 2; ++m) {
                    f32x4 z = __builtin_amdgcn_mfma_f32_16x16x32_bf16(ka[i][0], qt[m][0], zero, 0, 0, 0);
                    st[m][i] = __builtin_amdgcn_mfma_f32_16x16x32_bf16(ka[i][1], qt[m][1], z, 0, 0, 0);
                }
            if (kt + 1 == nkt - 1) {      // diagonal tile (last)
                const int kb = (kt + 1) * 64;
#pragma unroll
                for (int m = 0; m < 2; ++m)
#pragma unroll
                    for (int i = 0; i < 4; ++i)
#pragma unroll
                        for (int r = 0; r < 4; ++r)
                            if (kb + i * 16 + quad * 4 + r > q0 + m * 16 + l15)
                                st[m][i][r] = -INFINITY;
            }
            // ---- p = exp2(s); pack; write P(kt+1) to other buffer
#pragma unroll
            for (int m = 0; m < 2; ++m)
#pragma unroll
                for (int i = 0; i < 4; ++i) {
                    unsigned e0 = __float_as_uint(__builtin_amdgcn_exp2f(st[m][i][0])) + 0x8000u;
                    unsigned e1 = __float_as_uint(__builtin_amdgcn_exp2f(st[m][i][1])) + 0x8000u;
                    unsigned e2 = __float_as_uint(__builtin_amdgcn_exp2f(st[m][i][2])) + 0x8000u;
                    unsigned e3 = __float_as_uint(__builtin_amdgcn_exp2f(st[m][i][3])) + 0x8000u;
                    uint2 pk;
                    pk.x = __builtin_amdgcn_perm(e1, e0, 0x07060302);
                    pk.y = __builtin_amdgcn_perm(e3, e2, 0x07060302);
                    *(uint2*)(bn + pw_off + m * 16 * LDP + i * 16) = pk;
                }
        }
    }

    // ---- epilogue: each wave owns its 32 rows -> O / l -> Y bf16
    const int b = bh / 12, hd = bh % 12;
#pragma unroll
    for (int m = 0; m < 2; ++m)
#pragma unroll
        for (int r = 0; r < 4; ++r) {
            float inv = 1.0f / lac[m][r];
            int t = q0 + 16 * m + quad * 4 + r;
            size_t base = ((size_t)(b * 4096 + t)) * 768 + hd * 64;
#pragma unroll
            for (int dj = 0; dj < 4; ++dj)
                Y[base + dj * 16 + l15] = f2bf(O[m][dj][r] * inv);
        }
}

// ---------------- launch ----------------
extern "C" void kernel_launch(void* const* d_in, const int* in_sizes, int n_in,
                              void* d_out, int out_size, void* d_ws, size_t ws_size,
                              hipStream_t stream) {
    (void)in_sizes; (void)n_in; (void)out_size; (void)ws_size;
    const float* x     = (const float*)d_in[0];
    const float* Wqkv  = (const float*)d_in[1];
    const float* bqkv  = (const float*)d_in[2];
    const float* Wproj = (const float*)d_in[3];
    const float* bproj = (const float*)d_in[4];
    float* out = (float*)d_out;

    char* ws = (char*)d_ws;
    size_t off = 0;
    auto alloc = [&](size_t bytes) -> void* {
        void* p = ws + off;
        off += (bytes + 255) & ~(size_t)255;
        return p;
    };
    unsigned short* xb     = (unsigned short*)alloc((size_t)8192 * 768 * 2);
    unsigned short* WqkvT  = (unsigned short*)alloc((size_t)2304 * 768 * 2);
    unsigned short* WprojT = (unsigned short*)alloc((size_t)768 * 768 * 2);
    unsigned short* QLb    = (unsigned short*)alloc((size_t)24 * 4096 * 64 * 2);
    unsigned short* KLb    = (unsigned short*)alloc((size_t)24 * 4096 * 64 * 2);
    unsigned short* VLb    = (unsigned short*)alloc((size_t)24 * 4096 * 64 * 2);
    unsigned short* Yb     = (unsigned short*)alloc((size_t)8192 * 768 * 2);

    k_convert<<<6144, 256, 0, stream>>>(x, xb, 8192 * 768 / 4);
    dim3 tb(32, 8);
    k_transpose<<<dim3(72, 24), tb, 0, stream>>>(Wqkv, WqkvT, 768, 2304);
    k_transpose<<<dim3(24, 24), tb, 0, stream>>>(Wproj, WprojT, 768, 768);
    k_gemm_qkv<<<dim3(64, 18), 256, 0, stream>>>(xb, WqkvT, bqkv, QLb, KLb, VLb);
    k_attn<<<dim3(3072 / 2), 128, 0, stream>>>(QLb, KLb, VLb, Yb);
    k_gemm_proj<<<dim3(64, 6), 256, 0, stream>>>(Yb, WprojT, bproj, out);
}

// Round 10
// 240.003 us; speedup vs baseline: 1.2010x; 1.0126x over previous
//
#include <hip/hip_runtime.h>
#include <math.h>
#include <stdint.h>

// MFMA fragment types (guide §3, compile-verified on gfx950)
typedef __attribute__((ext_vector_type(8))) short bf16x8;   // 8 bf16 in 4 VGPRs
typedef __attribute__((ext_vector_type(4))) float f32x4;    // 4 fp32 acc

__device__ __forceinline__ unsigned short f2bf(float f) {
    union { float f; unsigned u; } v; v.f = f;
    return (unsigned short)((v.u + 0x7fffu + ((v.u >> 16) & 1u)) >> 16); // RNE
}

// pack two f32 -> 2x bf16 in one full-rate VALU op (T12 recipe; no builtin
// on gfx950, m240). D[15:0] = bf16(S0), D[31:16] = bf16(S1), RNE.
__device__ __forceinline__ unsigned cvt_pk_bf16(float lo, float hi) {
    unsigned r;
    asm("v_cvt_pk_bf16_f32 %0, %1, %2" : "=v"(r) : "v"(lo), "v"(hi));
    return r;
}

// async global->LDS, 16B per lane; LDS dest = firstlane base + lane*16 (m97)
__device__ __forceinline__ void gld_lds16(const void* g, void* l) {
    __builtin_amdgcn_global_load_lds(
        (const __attribute__((address_space(1))) unsigned*)(uintptr_t)g,
        (__attribute__((address_space(3))) unsigned*)(uintptr_t)l, 16, 0, 0);
}

// ---------------- fp32 -> bf16 elementwise (x4 vectorized) ----------------
__global__ void k_convert(const float* __restrict__ in, unsigned short* __restrict__ out, int n4) {
    int i = blockIdx.x * blockDim.x + threadIdx.x;
    if (i >= n4) return;
    float4 f = ((const float4*)in)[i];
    ushort4 o;
    o.x = f2bf(f.x); o.y = f2bf(f.y); o.z = f2bf(f.z); o.w = f2bf(f.w);
    ((ushort4*)out)[i] = o;
}

// ---------------- fp32 [R][C] -> bf16 [C][R] (tiled transpose) ----------------
__global__ void k_transpose(const float* __restrict__ in, unsigned short* __restrict__ out, int R, int C) {
    __shared__ float tile[32][33];
    int c0 = blockIdx.x * 32, r0 = blockIdx.y * 32;
    int tx = threadIdx.x, ty = threadIdx.y; // block (32,8)
#pragma unroll
    for (int i = 0; i < 4; ++i)
        tile[ty + i * 8][tx] = in[(size_t)(r0 + ty + i * 8) * C + c0 + tx];
    __syncthreads();
#pragma unroll
    for (int i = 0; i < 4; ++i)
        out[(size_t)(c0 + ty + i * 8) * R + r0 + tx] = f2bf(tile[tx][ty + i * 8]);
}

// ---------------- 128x128 bf16 MFMA GEMM core (m97-style staging) ----------
#define LDT 32

__device__ __forceinline__ void gemm_core(
    const unsigned short* __restrict__ A, const unsigned short* __restrict__ Bt,
    int K, unsigned short* As, unsigned short* Bs, f32x4 (&acc)[4][4])
{
    const int tid  = threadIdx.x;
    const int lane = tid & 63;
    const int w    = tid >> 6;
    const int wm   = (w >> 1) * 64, wn = (w & 1) * 64;
    const int l15  = lane & 15, quad = lane >> 4;
    const int m0 = blockIdx.x * 128, n0 = blockIdx.y * 128;

    const f32x4 zero = {0.f, 0.f, 0.f, 0.f};
#pragma unroll
    for (int i = 0; i < 4; ++i)
#pragma unroll
        for (int j = 0; j < 4; ++j) acc[i][j] = zero;

    const int r0 = tid >> 2, p8 = (tid & 3) * 8;
    const unsigned short* Ag0 = A  + (size_t)(m0 + r0) * K + p8;
    const unsigned short* Ag1 = A  + (size_t)(m0 + r0 + 64) * K + p8;
    const unsigned short* Bg0 = Bt + (size_t)(n0 + r0) * K + p8;
    const unsigned short* Bg1 = Bt + (size_t)(n0 + r0 + 64) * K + p8;
    unsigned short* lA0 = As + r0 * LDT + p8;          // byte offset tid*16
    unsigned short* lA1 = lA0 + 64 * LDT;
    unsigned short* lB0 = Bs + r0 * LDT + p8;
    unsigned short* lB1 = lB0 + 64 * LDT;

    const int nk = K >> 5;
    for (int kt = 0; kt < nk; ++kt) {
        __syncthreads();                    // LDS free (prev compute done)
        gld_lds16(Ag0, lA0);
        gld_lds16(Ag1, lA1);
        gld_lds16(Bg0, lB0);
        gld_lds16(Bg1, lB1);
        Ag0 += 32; Ag1 += 32; Bg0 += 32; Bg1 += 32;
        __syncthreads();                    // drains vmcnt -> data landed
        bf16x8 af[4], bfr[4];
#pragma unroll
        for (int mi = 0; mi < 4; ++mi)
            af[mi] = *(const bf16x8*)&As[(wm + mi * 16 + l15) * LDT + quad * 8];
#pragma unroll
        for (int nj = 0; nj < 4; ++nj)
            bfr[nj] = *(const bf16x8*)&Bs[(wn + nj * 16 + l15) * LDT + quad * 8];
#pragma unroll
        for (int mi = 0; mi < 4; ++mi)
#pragma unroll
            for (int nj = 0; nj < 4; ++nj)
                acc[mi][nj] = __builtin_amdgcn_mfma_f32_16x16x32_bf16(af[mi], bfr[nj], acc[mi][nj], 0, 0, 0);
    }
}

// QKV GEMM epilogue scatters into FRAGMENT-ORDER buffers so every attention
// global load is one coalesced 1024B block (base + lane*16B):
//  QL[bh][qi][m][h][lane][8]  : lane(l15,quad) holds Q[qi*32+16m+l15][32h+8quad+j]
//  KL[bh][t ][i][h][lane][8]  : lane holds K[64t+16i+l15][32h+8quad+j]
//  VL[bh][t ][dj][h][lane][8] : lane holds V[64t+32h+8quad+j][16dj+l15]
// Q pre-scaled by (1/8)*log2(e): softmax runs in exp2 domain.
__global__ __launch_bounds__(256) void k_gemm_qkv(
    const unsigned short* __restrict__ A, const unsigned short* __restrict__ Bt,
    const float* __restrict__ bias,
    unsigned short* __restrict__ QL, unsigned short* __restrict__ KL,
    unsigned short* __restrict__ VL)
{
    __shared__ __align__(16) unsigned short As[128 * LDT];
    __shared__ __align__(16) unsigned short Bs[128 * LDT];
    f32x4 acc[4][4];
    gemm_core(A, Bt, 768, As, Bs, acc);

    const int tid = threadIdx.x, lane = tid & 63, w = tid >> 6;
    const int wm = (w >> 1) * 64, wn = (w & 1) * 64;
    const int l15 = lane & 15, quad = lane >> 4;
    const int m0 = blockIdx.x * 128, n0 = blockIdx.y * 128;
    const float cscale = 0.18033688011f;  // (1/8) * log2(e)
#pragma unroll
    for (int nj = 0; nj < 4; ++nj) {
        int cg = n0 + wn + nj * 16 + l15;        // column in [0,2304)
        float bv = bias[cg];
        int which = cg / 768;                    // 0=q 1=k 2=v
        int rem = cg - which * 768;
        int hd = rem >> 6, d = rem & 63;
        float sc = (which == 0) ? cscale : 1.0f;
#pragma unroll
        for (int mi = 0; mi < 4; ++mi) {
#pragma unroll
            for (int r = 0; r < 4; ++r) {
                int rg = m0 + wm + mi * 16 + quad * 4 + r;   // row in [0,8192)
                int b = rg >> 12, tk = rg & 4095;
                int bh = b * 12 + hd;
                unsigned short ob = f2bf((acc[mi][nj][r] + bv) * sc);
                if (which == 0) {
                    size_t idx = ((((size_t)bh * 128 + (tk >> 5)) * 2 + ((tk >> 4) & 1)) * 2 + (d >> 5)) * 512
                               + ((d >> 3) & 3) * 128 + (tk & 15) * 8 + (d & 7);
                    QL[idx] = ob;
                } else if (which == 1) {
                    size_t idx = ((((size_t)bh * 64 + (tk >> 6)) * 4 + ((tk >> 4) & 3)) * 2 + (d >> 5)) * 512
                               + ((d >> 3) & 3) * 128 + (tk & 15) * 8 + (d & 7);
                    KL[idx] = ob;
                } else {
                    int wi = tk & 63;
                    size_t idx = ((((size_t)bh * 64 + (tk >> 6)) * 4 + (d >> 4)) * 2 + (wi >> 5)) * 512
                               + ((wi >> 3) & 3) * 128 + (d & 15) * 8 + (wi & 7);
                    VL[idx] = ob;
                }
            }
        }
    }
}

// Proj GEMM: A = y bf16 [8192][768], Bt = WprojT [768][768], out fp32 + bias
__global__ __launch_bounds__(256) void k_gemm_proj(
    const unsigned short* __restrict__ A, const unsigned short* __restrict__ Bt,
    const float* __restrict__ bias, float* __restrict__ out)
{
    __shared__ __align__(16) unsigned short As[128 * LDT];
    __shared__ __align__(16) unsigned short Bs[128 * LDT];
    f32x4 acc[4][4];
    gemm_core(A, Bt, 768, As, Bs, acc);

    const int tid = threadIdx.x, lane = tid & 63, w = tid >> 6;
    const int wm = (w >> 1) * 64, wn = (w & 1) * 64;
    const int l15 = lane & 15, quad = lane >> 4;
    const int m0 = blockIdx.x * 128, n0 = blockIdx.y * 128;
#pragma unroll
    for (int nj = 0; nj < 4; ++nj) {
        int cg = n0 + wn + nj * 16 + l15;
        float bv = bias[cg];
#pragma unroll
        for (int mi = 0; mi < 4; ++mi)
#pragma unroll
            for (int r = 0; r < 4; ++r) {
                int rg = m0 + wm + mi * 16 + quad * 4 + r;
                out[(size_t)rg * 768 + cg] = acc[mi][nj][r] + bv;
            }
    }
}

// -- Flash attention, causal, PAIRED-Q, BALANCED MAP + WAVE PRIORITY --------
// R11 = R10 (best attn, 85us) + VALU content reduction:
// (1) P-pack via v_cvt_pk_bf16_f32 (T12): per (m,i), 2 cvt_pk replace
//     4 v_add_u32 + 2 v_perm_b32 -> -32 VALU ops/iter (~17% of the ~392-cyc
//     VALU content, on the critical P-write path). RNE rounding (>= old
//     +0x8000 round-half-up accuracy). Operand order D[15:0]=bf16(S0)
//     matches old perm layout (low short = r=0).
// (2) ka(kt+1) issue hoisted ABOVE the P-LDS read: ~+100cyc extra latency
//     coverage for the K loads, free.
// Retained from R10: complement map g = j<32 ? j : 95-j (per-CU work 189+-2
// block-iters const); static wave priority g>>4 (critical-path waves issue
// first); 2 waves/block on ADJACENT q-tiles {2g,2g+1}, same key loop ->
// L1 sharing, no barrier, no combine; id%8 = bh%8 XCD-local K/V;
// one-iteration-skew pipeline, P dbuf in LDS, LDP=68 conflict-free.
#define LDP 68

__global__ __launch_bounds__(128) void k_attn(
    const unsigned short* __restrict__ QL, const unsigned short* __restrict__ KL,
    const unsigned short* __restrict__ VL, unsigned short* __restrict__ Y)
{
    // P dbuf: 2 waves x 2 bufs x 32*LDP shorts = 17408B (wave-private)
    __shared__ __align__(16) char smem[17408];
    unsigned short* Ps = (unsigned short*)smem;

    const int tid = threadIdx.x, lane = tid & 63;
    const int w = __builtin_amdgcn_readfirstlane(tid >> 6);   // wave-uniform, 0..1
    const int l15 = lane & 15, quad = lane >> 4;
    const int id = blockIdx.x;
    const int bh = id % 24;                   // id%8 = bh%8 -> XCD-local K/V
    const int j  = id / 24;                   // 0..63
    const int g  = (j < 32) ? j : 95 - j;     // complement map: per-CU work const
    const int qi = 2 * g + w;                 // this wave's 32-row q-tile
    const int q0 = qi * 32;
    const int nkt = g + 1;                    // key tiles; SAME for both waves
    unsigned short* Pw = Ps + w * 2 * 32 * LDP;   // this wave's two buffers

    // static priority: long (critical-path) waves issue first on their SIMD
    const int pr = g >> 4;
    if (pr == 3)      __builtin_amdgcn_s_setprio(3);
    else if (pr == 2) __builtin_amdgcn_s_setprio(2);
    else if (pr == 1) __builtin_amdgcn_s_setprio(1);

    const int pw_off = l15 * LDP + quad * 4;  // P write base (shorts)
    const int pr_off = l15 * LDP + quad * 8;  // P read base

    // fragment-chunk bases (each chunk = 512 shorts = 1024B, lane offset *8)
    const unsigned short* Qb = QL + (((size_t)bh * 128 + qi) * 4) * 512 + lane * 8;
    const unsigned short* kp = KL + ((size_t)bh * 64) * 4096 + lane * 8;
    const unsigned short* vp = VL + ((size_t)bh * 64) * 4096 + lane * 8;

    // Q^T B-fragments (chunk layout matches B-frag exactly)
    bf16x8 qt[2][2];
#pragma unroll
    for (int m = 0; m < 2; ++m)
#pragma unroll
        for (int h = 0; h < 2; ++h)
            qt[m][h] = *(const bf16x8*)(Qb + (m * 2 + h) * 512);

    const f32x4 zero = {0.f, 0.f, 0.f, 0.f};
    f32x4 O[2][4], lac[2];
#pragma unroll
    for (int m = 0; m < 2; ++m) {
        lac[m] = zero;
#pragma unroll
        for (int dj = 0; dj < 4; ++dj) O[m][dj] = zero;
    }

    const short ONE = (short)0x3F80;  // bf16 1.0
    const bf16x8 onesf = {ONE, ONE, ONE, ONE, ONE, ONE, ONE, ONE};

    bf16x8 ka[4][2], vf[4][2];
#pragma unroll
    for (int i = 0; i < 4; ++i)
#pragma unroll
        for (int h = 0; h < 2; ++h)
            ka[i][h] = *(const bf16x8*)(kp + (i * 2 + h) * 512);
#pragma unroll
    for (int dj = 0; dj < 4; ++dj)
#pragma unroll
        for (int h = 0; h < 2; ++h)
            vf[dj][h] = *(const bf16x8*)(vp + (dj * 2 + h) * 512);

    // ---- prologue: st(0) -> exp2 -> P buf0
    {
        f32x4 st[2][4];
#pragma unroll
        for (int i = 0; i < 4; ++i)
#pragma unroll
            for (int m = 0; m < 2; ++m) {
                f32x4 z = __builtin_amdgcn_mfma_f32_16x16x32_bf16(ka[i][0], qt[m][0], zero, 0, 0, 0);
                st[m][i] = __builtin_amdgcn_mfma_f32_16x16x32_bf16(ka[i][1], qt[m][1], z, 0, 0, 0);
            }
        if (nkt == 1) {                 // tile 0 is the diagonal tile
#pragma unroll
            for (int m = 0; m < 2; ++m)
#pragma unroll
                for (int i = 0; i < 4; ++i)
#pragma unroll
                    for (int r = 0; r < 4; ++r)
                        if (i * 16 + quad * 4 + r > q0 + m * 16 + l15)
                            st[m][i][r] = -INFINITY;
        }
#pragma unroll
        for (int m = 0; m < 2; ++m)
#pragma unroll
            for (int i = 0; i < 4; ++i) {
                uint2 pk;
                pk.x = cvt_pk_bf16(__builtin_amdgcn_exp2f(st[m][i][0]),
                                   __builtin_amdgcn_exp2f(st[m][i][1]));
                pk.y = cvt_pk_bf16(__builtin_amdgcn_exp2f(st[m][i][2]),
                                   __builtin_amdgcn_exp2f(st[m][i][3]));
                *(uint2*)(Pw + pw_off + m * 16 * LDP + i * 16) = pk;
            }
    }

    for (int kt = 0; kt < nkt; ++kt) {
        unsigned short* bc = Pw + (kt & 1) * 32 * LDP;
        unsigned short* bn = Pw + ((kt & 1) ^ 1) * 32 * LDP;
        const bool more = (kt + 1 < nkt);

        // ---- issue ka(kt+1) first (before P-read): max latency coverage
        if (more) {
            kp += 4096;
#pragma unroll
            for (int i = 0; i < 4; ++i)
#pragma unroll
                for (int h = 0; h < 2; ++h)
                    ka[i][h] = *(const bf16x8*)(kp + (i * 2 + h) * 512);
        }

        // ---- read P(kt) as A-frags (written last iter; no RAW stall)
        bf16x8 pa[2][2];
#pragma unroll
        for (int m = 0; m < 2; ++m) {
            pa[m][0] = *(const bf16x8*)(bc + pr_off + m * 16 * LDP);
            pa[m][1] = *(const bf16x8*)(bc + pr_off + m * 16 * LDP + 32);
        }

        // ---- l += P @ ones ; O += P V(kt)
#pragma unroll
        for (int m = 0; m < 2; ++m) {
            f32x4 z = __builtin_amdgcn_mfma_f32_16x16x32_bf16(pa[m][0], onesf, lac[m], 0, 0, 0);
            lac[m] = __builtin_amdgcn_mfma_f32_16x16x32_bf16(pa[m][1], onesf, z, 0, 0, 0);
        }
#pragma unroll
        for (int dj = 0; dj < 4; ++dj)
#pragma unroll
            for (int m = 0; m < 2; ++m) {
                f32x4 y = __builtin_amdgcn_mfma_f32_16x16x32_bf16(pa[m][0], vf[dj][0], O[m][dj], 0, 0, 0);
                O[m][dj] = __builtin_amdgcn_mfma_f32_16x16x32_bf16(pa[m][1], vf[dj][1], y, 0, 0, 0);
            }

        if (more) {
            // ---- issue vf(kt+1); latency covered by QK + exp2 below
            vp += 4096;
#pragma unroll
            for (int dj = 0; dj < 4; ++dj)
#pragma unroll
                for (int h = 0; h < 2; ++h)
                    vf[dj][h] = *(const bf16x8*)(vp + (dj * 2 + h) * 512);

            // ---- st(kt+1) = K Q^T (ka latency already covered)
            f32x4 st[2][4];
#pragma unroll
            for (int i = 0; i < 4; ++i)
#pragma unroll
                for (int m = 0; m < 2; ++m) {
                    f32x4 z = __builtin_amdgcn_mfma_f32_16x16x32_bf16(ka[i][0], qt[m][0], zero, 0, 0, 0);
                    st[m][i] = __builtin_amdgcn_mfma_f32_16x16x32_bf16(ka[i][1], qt[m][1], z, 0, 0, 0);
                }
            if (kt + 1 == nkt - 1) {      // diagonal tile (last)
                const int kb = (kt + 1) * 64;
#pragma unroll
                for (int m = 0; m < 2; ++m)
#pragma unroll
                    for (int i = 0; i < 4; ++i)
#pragma unroll
                        for (int r = 0; r < 4; ++r)
                            if (kb + i * 16 + quad * 4 + r > q0 + m * 16 + l15)
                                st[m][i][r] = -INFINITY;
            }
            // ---- p = exp2(s); cvt_pk pack; write P(kt+1) to other buffer
#pragma unroll
            for (int m = 0; m < 2; ++m)
#pragma unroll
                for (int i = 0; i < 4; ++i) {
                    uint2 pk;
                    pk.x = cvt_pk_bf16(__builtin_amdgcn_exp2f(st[m][i][0]),
                                       __builtin_amdgcn_exp2f(st[m][i][1]));
                    pk.y = cvt_pk_bf16(__builtin_amdgcn_exp2f(st[m][i][2]),
                                       __builtin_amdgcn_exp2f(st[m][i][3]));
                    *(uint2*)(bn + pw_off + m * 16 * LDP + i * 16) = pk;
                }
        }
    }

    // ---- epilogue: each wave owns its 32 rows -> O / l -> Y bf16
    const int b = bh / 12, hd = bh % 12;
#pragma unroll
    for (int m = 0; m < 2; ++m)
#pragma unroll
        for (int r = 0; r < 4; ++r) {
            float inv = 1.0f / lac[m][r];
            int t = q0 + 16 * m + quad * 4 + r;
            size_t base = ((size_t)(b * 4096 + t)) * 768 + hd * 64;
#pragma unroll
            for (int dj = 0; dj < 4; ++dj)
                Y[base + dj * 16 + l15] = f2bf(O[m][dj][r] * inv);
        }
}

// ---------------- launch ----------------
extern "C" void kernel_launch(void* const* d_in, const int* in_sizes, int n_in,
                              void* d_out, int out_size, void* d_ws, size_t ws_size,
                              hipStream_t stream) {
    (void)in_sizes; (void)n_in; (void)out_size; (void)ws_size;
    const float* x     = (const float*)d_in[0];
    const float* Wqkv  = (const float*)d_in[1];
    const float* bqkv  = (const float*)d_in[2];
    const float* Wproj = (const float*)d_in[3];
    const float* bproj = (const float*)d_in[4];
    float* out = (float*)d_out;

    char* ws = (char*)d_ws;
    size_t off = 0;
    auto alloc = [&](size_t bytes) -> void* {
        void* p = ws + off;
        off += (bytes + 255) & ~(size_t)255;
        return p;
    };
    unsigned short* xb     = (unsigned short*)alloc((size_t)8192 * 768 * 2);
    unsigned short* WqkvT  = (unsigned short*)alloc((size_t)2304 * 768 * 2);
    unsigned short* WprojT = (unsigned short*)alloc((size_t)768 * 768 * 2);
    unsigned short* QLb    = (unsigned short*)alloc((size_t)24 * 4096 * 64 * 2);
    unsigned short* KLb    = (unsigned short*)alloc((size_t)24 * 4096 * 64 * 2);
    unsigned short* VLb    = (unsigned short*)alloc((size_t)24 * 4096 * 64 * 2);
    unsigned short* Yb     = (unsigned short*)alloc((size_t)8192 * 768 * 2);

    k_convert<<<6144, 256, 0, stream>>>(x, xb, 8192 * 768 / 4);
    dim3 tb(32, 8);
    k_transpose<<<dim3(72, 24), tb, 0, stream>>>(Wqkv, WqkvT, 768, 2304);
    k_transpose<<<dim3(24, 24), tb, 0, stream>>>(Wproj, WprojT, 768, 768);
    k_gemm_qkv<<<dim3(64, 18), 256, 0, stream>>>(xb, WqkvT, bqkv, QLb, KLb, VLb);
    k_attn<<<dim3(3072 / 2), 128, 0, stream>>>(QLb, KLb, VLb, Yb);
    k_gemm_proj<<<dim3(64, 6), 256, 0, stream>>>(Yb, WprojT, bproj, out);
}

// Round 11
// 234.303 us; speedup vs baseline: 1.2302x; 1.0243x over previous
//
#include <hip/hip_runtime.h>
#include <math.h>
#include <stdint.h>

// MFMA fragment types (guide §3, compile-verified on gfx950)
typedef __attribute__((ext_vector_type(8))) short bf16x8;   // 8 bf16 in 4 VGPRs
typedef __attribute__((ext_vector_type(4))) float f32x4;    // 4 fp32 acc

__device__ __forceinline__ unsigned short f2bf(float f) {
    union { float f; unsigned u; } v; v.f = f;
    return (unsigned short)((v.u + 0x7fffu + ((v.u >> 16) & 1u)) >> 16); // RNE
}

// pack two f32 -> 2x bf16 in one full-rate VALU op (T12 recipe; no builtin
// on gfx950, m240). D[15:0] = bf16(S0), D[31:16] = bf16(S1), RNE.
__device__ __forceinline__ unsigned cvt_pk_bf16(float lo, float hi) {
    unsigned r;
    asm("v_cvt_pk_bf16_f32 %0, %1, %2" : "=v"(r) : "v"(lo), "v"(hi));
    return r;
}

// async global->LDS, 16B per lane; LDS dest = firstlane base + lane*16 (m97)
__device__ __forceinline__ void gld_lds16(const void* g, void* l) {
    __builtin_amdgcn_global_load_lds(
        (const __attribute__((address_space(1))) unsigned*)(uintptr_t)g,
        (__attribute__((address_space(3))) unsigned*)(uintptr_t)l, 16, 0, 0);
}

// ---------------- fused prep: convert + 2 transposes in ONE launch ----------
// R12: merge k_convert (6144 blocks) + k_transpose Wqkv (72x24) + k_transpose
// Wproj (24x24) -> one kernel, 6 launches -> 4 (launch-gap reduction).
// Dispatch is block-uniform (no divergence within a block).
__global__ __launch_bounds__(256) void k_prep(
    const float* __restrict__ x, unsigned short* __restrict__ xb,
    const float* __restrict__ Wqkv, unsigned short* __restrict__ WqkvT,
    const float* __restrict__ Wproj, unsigned short* __restrict__ WprojT)
{
    __shared__ float tile[32][33];
    const int id = blockIdx.x, tid = threadIdx.x;

    if (id < 6144) {
        // ---- fp32 -> bf16 elementwise (x4 vectorized), 8192*768 elems
        int i = id * 256 + tid;
        float4 f = ((const float4*)x)[i];
        ushort4 o;
        o.x = f2bf(f.x); o.y = f2bf(f.y); o.z = f2bf(f.z); o.w = f2bf(f.w);
        ((ushort4*)xb)[i] = o;
        return;
    }

    // ---- tiled transpose fp32 [R][C] -> bf16 [C][R]
    const float* in; unsigned short* out; int R, C, bx, by;
    if (id < 6144 + 1728) {          // Wqkv: R=768, C=2304, grid 72x24
        int bid = id - 6144;
        in = Wqkv; out = WqkvT; R = 768; C = 2304;
        bx = bid % 72; by = bid / 72;
    } else {                          // Wproj: R=768, C=768, grid 24x24
        int bid = id - 7872;
        in = Wproj; out = WprojT; R = 768; C = 768;
        bx = bid % 24; by = bid / 24;
    }
    const int tx = tid & 31, ty = tid >> 5;   // (32,8) layout
    const int c0 = bx * 32, r0 = by * 32;
#pragma unroll
    for (int i = 0; i < 4; ++i)
        tile[ty + i * 8][tx] = in[(size_t)(r0 + ty + i * 8) * C + c0 + tx];
    __syncthreads();
#pragma unroll
    for (int i = 0; i < 4; ++i)
        out[(size_t)(c0 + ty + i * 8) * R + r0 + tx] = f2bf(tile[tx][ty + i * 8]);
}

// ---------------- 128x128 bf16 MFMA GEMM core (m97-style staging) ----------
// R12: LDS bank-conflict fix per rule #21 (both-sides-or-neither with
// global_load_lds): dest stays LINEAR (base + tid*16B, required by HW);
// the global SOURCE chunk is swizzled kc = (tid&3)^(r0&3) (same 64B row,
// lane-order permuted -> coalescing unchanged); fragment ds_read_b128 XORs
// the slot back: quad^(l15&3). XORs cancel (data = chunk quad exactly).
// Effect: per-8-lane service group, slot pattern goes {0,4,0,4..} (4-way,
// 1.58x, m136) -> {0,5,2,7,0,5,2,7} (2-way = free). Addresses m98's 1.7e7
// conflict cycles in this structure.
#define LDT 32

__device__ __forceinline__ void gemm_core(
    const unsigned short* __restrict__ A, const unsigned short* __restrict__ Bt,
    int K, unsigned short* As, unsigned short* Bs, f32x4 (&acc)[4][4])
{
    const int tid  = threadIdx.x;
    const int lane = tid & 63;
    const int w    = tid >> 6;
    const int wm   = (w >> 1) * 64, wn = (w & 1) * 64;
    const int l15  = lane & 15, quad = lane >> 4;
    const int m0 = blockIdx.x * 128, n0 = blockIdx.y * 128;

    const f32x4 zero = {0.f, 0.f, 0.f, 0.f};
#pragma unroll
    for (int i = 0; i < 4; ++i)
#pragma unroll
        for (int j = 0; j < 4; ++j) acc[i][j] = zero;

    const int r0 = tid >> 2;
    const int p8c = (((tid & 3) ^ (r0 & 3))) * 8;      // swizzled source chunk
    const unsigned short* Ag0 = A  + (size_t)(m0 + r0) * K + p8c;
    const unsigned short* Ag1 = A  + (size_t)(m0 + r0 + 64) * K + p8c;
    const unsigned short* Bg0 = Bt + (size_t)(n0 + r0) * K + p8c;
    const unsigned short* Bg1 = Bt + (size_t)(n0 + r0 + 64) * K + p8c;
    unsigned short* lA0 = As + r0 * LDT + (tid & 3) * 8;   // linear dest tid*16B
    unsigned short* lA1 = lA0 + 64 * LDT;
    unsigned short* lB0 = Bs + r0 * LDT + (tid & 3) * 8;
    unsigned short* lB1 = lB0 + 64 * LDT;

    const int swA = (l15 & 3);          // read-side XOR (row&3; wm,mi*16 are %4==0)
    const int nk = K >> 5;
    for (int kt = 0; kt < nk; ++kt) {
        __syncthreads();                    // LDS free (prev compute done)
        gld_lds16(Ag0, lA0);
        gld_lds16(Ag1, lA1);
        gld_lds16(Bg0, lB0);
        gld_lds16(Bg1, lB1);
        Ag0 += 32; Ag1 += 32; Bg0 += 32; Bg1 += 32;
        __syncthreads();                    // drains vmcnt -> data landed
        bf16x8 af[4], bfr[4];
#pragma unroll
        for (int mi = 0; mi < 4; ++mi)
            af[mi] = *(const bf16x8*)&As[(wm + mi * 16 + l15) * LDT + ((quad ^ swA) * 8)];
#pragma unroll
        for (int nj = 0; nj < 4; ++nj)
            bfr[nj] = *(const bf16x8*)&Bs[(wn + nj * 16 + l15) * LDT + ((quad ^ swA) * 8)];
#pragma unroll
        for (int mi = 0; mi < 4; ++mi)
#pragma unroll
            for (int nj = 0; nj < 4; ++nj)
                acc[mi][nj] = __builtin_amdgcn_mfma_f32_16x16x32_bf16(af[mi], bfr[nj], acc[mi][nj], 0, 0, 0);
    }
}

// QKV GEMM epilogue scatters into FRAGMENT-ORDER buffers so every attention
// global load is one coalesced 1024B block (base + lane*16B):
//  QL[bh][qi][m][h][lane][8]  : lane(l15,quad) holds Q[qi*32+16m+l15][32h+8quad+j]
//  KL[bh][t ][i][h][lane][8]  : lane holds K[64t+16i+l15][32h+8quad+j]
//  VL[bh][t ][dj][h][lane][8] : lane holds V[64t+32h+8quad+j][16dj+l15]
// Q pre-scaled by (1/8)*log2(e): softmax runs in exp2 domain.
__global__ __launch_bounds__(256) void k_gemm_qkv(
    const unsigned short* __restrict__ A, const unsigned short* __restrict__ Bt,
    const float* __restrict__ bias,
    unsigned short* __restrict__ QL, unsigned short* __restrict__ KL,
    unsigned short* __restrict__ VL)
{
    __shared__ __align__(16) unsigned short As[128 * LDT];
    __shared__ __align__(16) unsigned short Bs[128 * LDT];
    f32x4 acc[4][4];
    gemm_core(A, Bt, 768, As, Bs, acc);

    const int tid = threadIdx.x, lane = tid & 63, w = tid >> 6;
    const int wm = (w >> 1) * 64, wn = (w & 1) * 64;
    const int l15 = lane & 15, quad = lane >> 4;
    const int m0 = blockIdx.x * 128, n0 = blockIdx.y * 128;
    const float cscale = 0.18033688011f;  // (1/8) * log2(e)
#pragma unroll
    for (int nj = 0; nj < 4; ++nj) {
        int cg = n0 + wn + nj * 16 + l15;        // column in [0,2304)
        float bv = bias[cg];
        int which = cg / 768;                    // 0=q 1=k 2=v
        int rem = cg - which * 768;
        int hd = rem >> 6, d = rem & 63;
        float sc = (which == 0) ? cscale : 1.0f;
#pragma unroll
        for (int mi = 0; mi < 4; ++mi) {
#pragma unroll
            for (int r = 0; r < 4; ++r) {
                int rg = m0 + wm + mi * 16 + quad * 4 + r;   // row in [0,8192)
                int b = rg >> 12, tk = rg & 4095;
                int bh = b * 12 + hd;
                unsigned short ob = f2bf((acc[mi][nj][r] + bv) * sc);
                if (which == 0) {
                    size_t idx = ((((size_t)bh * 128 + (tk >> 5)) * 2 + ((tk >> 4) & 1)) * 2 + (d >> 5)) * 512
                               + ((d >> 3) & 3) * 128 + (tk & 15) * 8 + (d & 7);
                    QL[idx] = ob;
                } else if (which == 1) {
                    size_t idx = ((((size_t)bh * 64 + (tk >> 6)) * 4 + ((tk >> 4) & 3)) * 2 + (d >> 5)) * 512
                               + ((d >> 3) & 3) * 128 + (tk & 15) * 8 + (d & 7);
                    KL[idx] = ob;
                } else {
                    int wi = tk & 63;
                    size_t idx = ((((size_t)bh * 64 + (tk >> 6)) * 4 + (d >> 4)) * 2 + (wi >> 5)) * 512
                               + ((wi >> 3) & 3) * 128 + (d & 15) * 8 + (wi & 7);
                    VL[idx] = ob;
                }
            }
        }
    }
}

// Proj GEMM: A = y bf16 [8192][768], Bt = WprojT [768][768], out fp32 + bias
__global__ __launch_bounds__(256) void k_gemm_proj(
    const unsigned short* __restrict__ A, const unsigned short* __restrict__ Bt,
    const float* __restrict__ bias, float* __restrict__ out)
{
    __shared__ __align__(16) unsigned short As[128 * LDT];
    __shared__ __align__(16) unsigned short Bs[128 * LDT];
    f32x4 acc[4][4];
    gemm_core(A, Bt, 768, As, Bs, acc);

    const int tid = threadIdx.x, lane = tid & 63, w = tid >> 6;
    const int wm = (w >> 1) * 64, wn = (w & 1) * 64;
    const int l15 = lane & 15, quad = lane >> 4;
    const int m0 = blockIdx.x * 128, n0 = blockIdx.y * 128;
#pragma unroll
    for (int nj = 0; nj < 4; ++nj) {
        int cg = n0 + wn + nj * 16 + l15;
        float bv = bias[cg];
#pragma unroll
        for (int mi = 0; mi < 4; ++mi)
#pragma unroll
            for (int r = 0; r < 4; ++r) {
                int rg = m0 + wm + mi * 16 + quad * 4 + r;
                out[(size_t)rg * 768 + cg] = acc[mi][nj][r] + bv;
            }
    }
}

// -- Flash attention, causal, PAIRED-Q, BALANCED MAP + WAVE PRIORITY --------
// R12 = R11 unchanged (best attn, 82.3us): cvt_pk pack, ka-hoist, complement
// map g = j<32 ? j : 95-j, static priority g>>4, 2 waves/block on adjacent
// q-tiles {2g,2g+1} (L1 sharing, no barrier, no combine), id%8 = bh%8
// XCD-local K/V, one-iteration-skew pipeline, P dbuf in LDS, LDP=68.
#define LDP 68

__global__ __launch_bounds__(128) void k_attn(
    const unsigned short* __restrict__ QL, const unsigned short* __restrict__ KL,
    const unsigned short* __restrict__ VL, unsigned short* __restrict__ Y)
{
    // P dbuf: 2 waves x 2 bufs x 32*LDP shorts = 17408B (wave-private)
    __shared__ __align__(16) char smem[17408];
    unsigned short* Ps = (unsigned short*)smem;

    const int tid = threadIdx.x, lane = tid & 63;
    const int w = __builtin_amdgcn_readfirstlane(tid >> 6);   // wave-uniform, 0..1
    const int l15 = lane & 15, quad = lane >> 4;
    const int id = blockIdx.x;
    const int bh = id % 24;                   // id%8 = bh%8 -> XCD-local K/V
    const int j  = id / 24;                   // 0..63
    const int g  = (j < 32) ? j : 95 - j;     // complement map: per-CU work const
    const int qi = 2 * g + w;                 // this wave's 32-row q-tile
    const int q0 = qi * 32;
    const int nkt = g + 1;                    // key tiles; SAME for both waves
    unsigned short* Pw = Ps + w * 2 * 32 * LDP;   // this wave's two buffers

    // static priority: long (critical-path) waves issue first on their SIMD
    const int pr = g >> 4;
    if (pr == 3)      __builtin_amdgcn_s_setprio(3);
    else if (pr == 2) __builtin_amdgcn_s_setprio(2);
    else if (pr == 1) __builtin_amdgcn_s_setprio(1);

    const int pw_off = l15 * LDP + quad * 4;  // P write base (shorts)
    const int pr_off = l15 * LDP + quad * 8;  // P read base

    // fragment-chunk bases (each chunk = 512 shorts = 1024B, lane offset *8)
    const unsigned short* Qb = QL + (((size_t)bh * 128 + qi) * 4) * 512 + lane * 8;
    const unsigned short* kp = KL + ((size_t)bh * 64) * 4096 + lane * 8;
    const unsigned short* vp = VL + ((size_t)bh * 64) * 4096 + lane * 8;

    // Q^T B-fragments (chunk layout matches B-frag exactly)
    bf16x8 qt[2][2];
#pragma unroll
    for (int m = 0; m < 2; ++m)
#pragma unroll
        for (int h = 0; h < 2; ++h)
            qt[m][h] = *(const bf16x8*)(Qb + (m * 2 + h) * 512);

    const f32x4 zero = {0.f, 0.f, 0.f, 0.f};
    f32x4 O[2][4], lac[2];
#pragma unroll
    for (int m = 0; m < 2; ++m) {
        lac[m] = zero;
#pragma unroll
        for (int dj = 0; dj < 4; ++dj) O[m][dj] = zero;
    }

    const short ONE = (short)0x3F80;  // bf16 1.0
    const bf16x8 onesf = {ONE, ONE, ONE, ONE, ONE, ONE, ONE, ONE};

    bf16x8 ka[4][2], vf[4][2];
#pragma unroll
    for (int i = 0; i < 4; ++i)
#pragma unroll
        for (int h = 0; h < 2; ++h)
            ka[i][h] = *(const bf16x8*)(kp + (i * 2 + h) * 512);
#pragma unroll
    for (int dj = 0; dj < 4; ++dj)
#pragma unroll
        for (int h = 0; h < 2; ++h)
            vf[dj][h] = *(const bf16x8*)(vp + (dj * 2 + h) * 512);

    // ---- prologue: st(0) -> exp2 -> P buf0
    {
        f32x4 st[2][4];
#pragma unroll
        for (int i = 0; i < 4; ++i)
#pragma unroll
            for (int m = 0; m < 2; ++m) {
                f32x4 z = __builtin_amdgcn_mfma_f32_16x16x32_bf16(ka[i][0], qt[m][0], zero, 0, 0, 0);
                st[m][i] = __builtin_amdgcn_mfma_f32_16x16x32_bf16(ka[i][1], qt[m][1], z, 0, 0, 0);
            }
        if (nkt == 1) {                 // tile 0 is the diagonal tile
#pragma unroll
            for (int m = 0; m < 2; ++m)
#pragma unroll
                for (int i = 0; i < 4; ++i)
#pragma unroll
                    for (int r = 0; r < 4; ++r)
                        if (i * 16 + quad * 4 + r > q0 + m * 16 + l15)
                            st[m][i][r] = -INFINITY;
        }
#pragma unroll
        for (int m = 0; m < 2; ++m)
#pragma unroll
            for (int i = 0; i < 4; ++i) {
                uint2 pk;
                pk.x = cvt_pk_bf16(__builtin_amdgcn_exp2f(st[m][i][0]),
                                   __builtin_amdgcn_exp2f(st[m][i][1]));
                pk.y = cvt_pk_bf16(__builtin_amdgcn_exp2f(st[m][i][2]),
                                   __builtin_amdgcn_exp2f(st[m][i][3]));
                *(uint2*)(Pw + pw_off + m * 16 * LDP + i * 16) = pk;
            }
    }

    for (int kt = 0; kt < nkt; ++kt) {
        unsigned short* bc = Pw + (kt & 1) * 32 * LDP;
        unsigned short* bn = Pw + ((kt & 1) ^ 1) * 32 * LDP;
        const bool more = (kt + 1 < nkt);

        // ---- issue ka(kt+1) first (before P-read): max latency coverage
        if (more) {
            kp += 4096;
#pragma unroll
            for (int i = 0; i < 4; ++i)
#pragma unroll
                for (int h = 0; h < 2; ++h)
                    ka[i][h] = *(const bf16x8*)(kp + (i * 2 + h) * 512);
        }

        // ---- read P(kt) as A-frags (written last iter; no RAW stall)
        bf16x8 pa[2][2];
#pragma unroll
        for (int m = 0; m < 2; ++m) {
            pa[m][0] = *(const bf16x8*)(bc + pr_off + m * 16 * LDP);
            pa[m][1] = *(const bf16x8*)(bc + pr_off + m * 16 * LDP + 32);
        }

        // ---- l += P @ ones ; O += P V(kt)
#pragma unroll
        for (int m = 0; m < 2; ++m) {
            f32x4 z = __builtin_amdgcn_mfma_f32_16x16x32_bf16(pa[m][0], onesf, lac[m], 0, 0, 0);
            lac[m] = __builtin_amdgcn_mfma_f32_16x16x32_bf16(pa[m][1], onesf, z, 0, 0, 0);
        }
#pragma unroll
        for (int dj = 0; dj < 4; ++dj)
#pragma unroll
            for (int m = 0; m < 2; ++m) {
                f32x4 y = __builtin_amdgcn_mfma_f32_16x16x32_bf16(pa[m][0], vf[dj][0], O[m][dj], 0, 0, 0);
                O[m][dj] = __builtin_amdgcn_mfma_f32_16x16x32_bf16(pa[m][1], vf[dj][1], y, 0, 0, 0);
            }

        if (more) {
            // ---- issue vf(kt+1); latency covered by QK + exp2 below
            vp += 4096;
#pragma unroll
            for (int dj = 0; dj < 4; ++dj)
#pragma unroll
                for (int h = 0; h < 2; ++h)
                    vf[dj][h] = *(const bf16x8*)(vp + (dj * 2 + h) * 512);

            // ---- st(kt+1) = K Q^T (ka latency already covered)
            f32x4 st[2][4];
#pragma unroll
            for (int i = 0; i < 4; ++i)
#pragma unroll
                for (int m = 0; m < 2; ++m) {
                    f32x4 z = __builtin_amdgcn_mfma_f32_16x16x32_bf16(ka[i][0], qt[m][0], zero, 0, 0, 0);
                    st[m][i] = __builtin_amdgcn_mfma_f32_16x16x32_bf16(ka[i][1], qt[m][1], z, 0, 0, 0);
                }
            if (kt + 1 == nkt - 1) {      // diagonal tile (last)
                const int kb = (kt + 1) * 64;
#pragma unroll
                for (int m = 0; m < 2; ++m)
#pragma unroll
                    for (int i = 0; i < 4; ++i)
#pragma unroll
                        for (int r = 0; r < 4; ++r)
                            if (kb + i * 16 + quad * 4 + r > q0 + m * 16 + l15)
                                st[m][i][r] = -INFINITY;
            }
            // ---- p = exp2(s); cvt_pk pack; write P(kt+1) to other buffer
#pragma unroll
            for (int m = 0; m < 2; ++m)
#pragma unroll
                for (int i = 0; i < 4; ++i) {
                    uint2 pk;
                    pk.x = cvt_pk_bf16(__builtin_amdgcn_exp2f(st[m][i][0]),
                                       __builtin_amdgcn_exp2f(st[m][i][1]));
                    pk.y = cvt_pk_bf16(__builtin_amdgcn_exp2f(st[m][i][2]),
                                       __builtin_amdgcn_exp2f(st[m][i][3]));
                    *(uint2*)(bn + pw_off + m * 16 * LDP + i * 16) = pk;
                }
        }
    }

    // ---- epilogue: each wave owns its 32 rows -> O / l -> Y bf16
    const int b = bh / 12, hd = bh % 12;
#pragma unroll
    for (int m = 0; m < 2; ++m)
#pragma unroll
        for (int r = 0; r < 4; ++r) {
            float inv = 1.0f / lac[m][r];
            int t = q0 + 16 * m + quad * 4 + r;
            size_t base = ((size_t)(b * 4096 + t)) * 768 + hd * 64;
#pragma unroll
            for (int dj = 0; dj < 4; ++dj)
                Y[base + dj * 16 + l15] = f2bf(O[m][dj][r] * inv);
        }
}

// ---------------- launch ----------------
extern "C" void kernel_launch(void* const* d_in, const int* in_sizes, int n_in,
                              void* d_out, int out_size, void* d_ws, size_t ws_size,
                              hipStream_t stream) {
    (void)in_sizes; (void)n_in; (void)out_size; (void)ws_size;
    const float* x     = (const float*)d_in[0];
    const float* Wqkv  = (const float*)d_in[1];
    const float* bqkv  = (const float*)d_in[2];
    const float* Wproj = (const float*)d_in[3];
    const float* bproj = (const float*)d_in[4];
    float* out = (float*)d_out;

    char* ws = (char*)d_ws;
    size_t off = 0;
    auto alloc = [&](size_t bytes) -> void* {
        void* p = ws + off;
        off += (bytes + 255) & ~(size_t)255;
        return p;
    };
    unsigned short* xb     = (unsigned short*)alloc((size_t)8192 * 768 * 2);
    unsigned short* WqkvT  = (unsigned short*)alloc((size_t)2304 * 768 * 2);
    unsigned short* WprojT = (unsigned short*)alloc((size_t)768 * 768 * 2);
    unsigned short* QLb    = (unsigned short*)alloc((size_t)24 * 4096 * 64 * 2);
    unsigned short* KLb    = (unsigned short*)alloc((size_t)24 * 4096 * 64 * 2);
    unsigned short* VLb    = (unsigned short*)alloc((size_t)24 * 4096 * 64 * 2);
    unsigned short* Yb     = (unsigned short*)alloc((size_t)8192 * 768 * 2);

    // prep: 6144 convert blocks + 1728 WqkvT + 576 WprojT = 8448
    k_prep<<<8448, 256, 0, stream>>>(x, xb, Wqkv, WqkvT, Wproj, WprojT);
    k_gemm_qkv<<<dim3(64, 18), 256, 0, stream>>>(xb, WqkvT, bqkv, QLb, KLb, VLb);
    k_attn<<<dim3(3072 / 2), 128, 0, stream>>>(QLb, KLb, VLb, Yb);
    k_gemm_proj<<<dim3(64, 6), 256, 0, stream>>>(Yb, WprojT, bproj, out);
}